// Round 1
// baseline (994.654 us; speedup 1.0000x reference)
//
#include <hip/hip_runtime.h>
#include <hip/hip_bf16.h>
#include <math.h>

typedef unsigned int u32;
typedef unsigned short u16;
using bf16x8 = __attribute__((ext_vector_type(8))) short;
using f32x4 = __attribute__((ext_vector_type(4))) float;

#define MFMA_BF16(a, b, c) __builtin_amdgcn_mfma_f32_16x16x32_bf16((a), (b), (c), 0, 0, 0)

constexpr int kS = 2048, kD = 1024, kH = 16, kE = 8, kFF = 4096;
constexpr int kSlots = kS * 2;  // 4096 (token, expert) slots, top-2 routing

// ---------- numeric helpers ----------
__device__ __forceinline__ u16 bf16_rne(float f) {
  u32 u = __float_as_uint(f);
  u32 r = (u + 0x7fffu + ((u >> 16) & 1u)) >> 16;
  return (u16)r;
}
__device__ __forceinline__ float bf16_f32(u16 h) { return __uint_as_float(((u32)h) << 16); }
// pack f32 as hi/lo bf16 pair in one u32 (lo16 bits = hi part, hi16 bits = lo part)
__device__ __forceinline__ u32 pack_hl(float x) {
  u16 hi = bf16_rne(x);
  u16 lo = bf16_rne(x - bf16_f32(hi));
  return ((u32)lo << 16) | (u32)hi;
}
__device__ __forceinline__ void unpack8(const u32* t, bf16x8& h, bf16x8& l) {
#pragma unroll
  for (int j = 0; j < 8; j++) {
    h[j] = (short)(t[j] & 0xffffu);
    l[j] = (short)(t[j] >> 16);
  }
}

// ---------- weight hi/lo split ----------
__global__ void pack_kernel(const float* __restrict__ w, u32* __restrict__ o, int n) {
  int i = blockIdx.x * 256 + threadIdx.x;
  if (i < n) o[i] = pack_hl(w[i]);
}

// ---------- RMSNorm (f32-exact). MODE 0: write packed hi/lo. MODE 1: write f32 + bf16 ----------
template <int MODE>
__global__ __launch_bounds__(256) void rmsnorm_kernel(
    const float* __restrict__ x, const float* __restrict__ scale,
    u32* __restrict__ opk, float* __restrict__ of32, u16* __restrict__ ob16) {
  const int s = blockIdx.x;
  const float* row = x + (size_t)s * kD;
  const int c = threadIdx.x * 4;
  float4 v = *(const float4*)(row + c);
  float ss = v.x * v.x + v.y * v.y + v.z * v.z + v.w * v.w;
#pragma unroll
  for (int m = 32; m; m >>= 1) ss += __shfl_xor(ss, m);
  __shared__ float wsum[4];
  if ((threadIdx.x & 63) == 0) wsum[threadIdx.x >> 6] = ss;
  __syncthreads();
  float tot = wsum[0] + wsum[1] + wsum[2] + wsum[3];
  float rinv = 1.0f / sqrtf(tot * (1.0f / kD) + 1e-5f);
  float4 sc = *(const float4*)(scale + c);
  float n0 = v.x * rinv * sc.x, n1 = v.y * rinv * sc.y;
  float n2 = v.z * rinv * sc.z, n3 = v.w * rinv * sc.w;
  if (MODE == 0) {
    u32* o = opk + (size_t)s * kD + c;
    o[0] = pack_hl(n0); o[1] = pack_hl(n1); o[2] = pack_hl(n2); o[3] = pack_hl(n3);
  } else {
    *(float4*)(of32 + (size_t)s * kD + c) = make_float4(n0, n1, n2, n3);
    u16* o = ob16 + (size_t)s * kD + c;
    o[0] = bf16_rne(n0); o[1] = bf16_rne(n1); o[2] = bf16_rne(n2); o[3] = bf16_rne(n3);
  }
}

// ---------- split-bf16 4-term GEMM: C[m,n] = sum_k A[m,k]*B[n,k], ~f32 precision ----------
// A,B are hi/lo-packed u32 [M][K], [N][K]. MODE 0: C -> packed u32. MODE 1: C -> f32 = resid + C.
template <int MODE>
__global__ __launch_bounds__(256) void gemm_split(
    const u32* __restrict__ A, const u32* __restrict__ B, int M, int N, int K,
    u32* __restrict__ Cpk, const float* __restrict__ resid, float* __restrict__ Cf) {
  constexpr int LDT = 36;  // padded u32 stride (144B: 16B-aligned, conflict-light)
  __shared__ u32 As[128 * LDT];
  __shared__ u32 Bs[128 * LDT];
  const int tid = threadIdx.x;
  const int w = tid >> 6, l = tid & 63;
  const int m0 = blockIdx.y * 128, n0 = blockIdx.x * 128;
  const int wr = (w >> 1) * 64, wc = (w & 1) * 64;
  f32x4 zero = {0.f, 0.f, 0.f, 0.f};
  f32x4 acc[4][4];
#pragma unroll
  for (int i = 0; i < 4; i++)
#pragma unroll
    for (int j = 0; j < 4; j++) acc[i][j] = zero;

  const int srow = tid >> 1, scol = (tid & 1) * 16;  // each thread stages 16 u32 of A and B
  const u32* gA = A + (size_t)(m0 + srow) * K + scol;
  const u32* gB = B + (size_t)(n0 + srow) * K + scol;
  u32* sA = As + srow * LDT + scol;
  u32* sB = Bs + srow * LDT + scol;

  for (int k0 = 0; k0 < K; k0 += 32) {
    uint4 a0 = *(const uint4*)(gA + k0);
    uint4 a1 = *(const uint4*)(gA + k0 + 4);
    uint4 a2 = *(const uint4*)(gA + k0 + 8);
    uint4 a3 = *(const uint4*)(gA + k0 + 12);
    uint4 b0 = *(const uint4*)(gB + k0);
    uint4 b1 = *(const uint4*)(gB + k0 + 4);
    uint4 b2 = *(const uint4*)(gB + k0 + 8);
    uint4 b3 = *(const uint4*)(gB + k0 + 12);
    __syncthreads();
    *(uint4*)(sA) = a0; *(uint4*)(sA + 4) = a1; *(uint4*)(sA + 8) = a2; *(uint4*)(sA + 12) = a3;
    *(uint4*)(sB) = b0; *(uint4*)(sB + 4) = b1; *(uint4*)(sB + 8) = b2; *(uint4*)(sB + 12) = b3;
    __syncthreads();

    bf16x8 ah[4], al[4], bh[4], bl[4];
#pragma unroll
    for (int i = 0; i < 4; i++) {
      u32 t[8];
      const u32* pa = As + (wr + i * 16 + (l & 15)) * LDT + ((l >> 4) << 3);
      *(uint4*)t = *(const uint4*)pa;
      *(uint4*)(t + 4) = *(const uint4*)(pa + 4);
      unpack8(t, ah[i], al[i]);
      const u32* pb = Bs + (wc + i * 16 + (l & 15)) * LDT + ((l >> 4) << 3);
      *(uint4*)t = *(const uint4*)pb;
      *(uint4*)(t + 4) = *(const uint4*)(pb + 4);
      unpack8(t, bh[i], bl[i]);
    }
#pragma unroll
    for (int mi = 0; mi < 4; mi++)
#pragma unroll
      for (int ni = 0; ni < 4; ni++) {
        f32x4 c = acc[mi][ni];
        c = MFMA_BF16(al[mi], bl[ni], c);
        c = MFMA_BF16(al[mi], bh[ni], c);
        c = MFMA_BF16(ah[mi], bl[ni], c);
        c = MFMA_BF16(ah[mi], bh[ni], c);
        acc[mi][ni] = c;
      }
  }
#pragma unroll
  for (int mi = 0; mi < 4; mi++)
#pragma unroll
    for (int ni = 0; ni < 4; ni++)
#pragma unroll
      for (int r = 0; r < 4; r++) {
        int row = m0 + wr + mi * 16 + ((l >> 4) << 2) + r;
        int col = n0 + wc + ni * 16 + (l & 15);
        float v = acc[mi][ni][r];
        if (MODE == 0) Cpk[(size_t)row * N + col] = pack_hl(v);
        else Cf[(size_t)row * N + col] = resid[(size_t)row * N + col] + v;
      }
}

// ---------- flash attention, causal, split-bf16 4-term, ~f32 precision ----------
// Q/K/V/O: hi/lo-packed u32 [2048][1024], head h at cols h*64..h*64+63.
__global__ __launch_bounds__(256) void attn_kernel(
    const u32* __restrict__ Qp, const u32* __restrict__ Kp, const u32* __restrict__ Vp,
    u32* __restrict__ Op) {
  constexpr int LDK = 68;  // padded u32 stride (272B)
  __shared__ u32 Ks[64 * LDK];  // Ks[t][dk]
  __shared__ u32 Vs[64 * LDK];  // transposed: Vs[dk][t]
  __shared__ u32 Ps[64 * LDK];  // per-wave rows [w*16, w*16+16)
  const int tid = threadIdx.x, w = tid >> 6, l = tid & 63;
  const int qt = blockIdx.x, hh = blockIdx.y;
  const int q0 = qt * 64, hc = hh * 64;

  bf16x8 qh[2], ql[2];
  {
    const int qrow = q0 + w * 16 + (l & 15);
#pragma unroll
    for (int kk = 0; kk < 2; kk++) {
      u32 t[8];
      const u32* p = Qp + (size_t)qrow * kD + hc + kk * 32 + ((l >> 4) << 3);
      *(uint4*)t = *(const uint4*)p;
      *(uint4*)(t + 4) = *(const uint4*)(p + 4);
      unpack8(t, qh[kk], ql[kk]);
    }
  }
  float mrun[4], lrun[4];
  f32x4 zero = {0.f, 0.f, 0.f, 0.f};
  f32x4 oacc[4];
#pragma unroll
  for (int r = 0; r < 4; r++) { mrun[r] = -3.0e38f; lrun[r] = 0.f; }
#pragma unroll
  for (int vb = 0; vb < 4; vb++) oacc[vb] = zero;

  for (int kt = 0; kt <= qt; kt++) {
    __syncthreads();
    {  // stage K (direct) and V (transposed)
      const int trow = tid >> 2, c0 = (tid & 3) * 16;
      const u32* gK = Kp + (size_t)(kt * 64 + trow) * kD + hc + c0;
      u32* sK = Ks + trow * LDK + c0;
      *(uint4*)sK = *(const uint4*)gK;
      *(uint4*)(sK + 4) = *(const uint4*)(gK + 4);
      *(uint4*)(sK + 8) = *(const uint4*)(gK + 8);
      *(uint4*)(sK + 12) = *(const uint4*)(gK + 12);
      const u32* gV = Vp + (size_t)(kt * 64 + trow) * kD + hc + c0;
#pragma unroll
      for (int j = 0; j < 16; j += 4) {
        uint4 v = *(const uint4*)(gV + j);
        Vs[(c0 + j + 0) * LDK + trow] = v.x;
        Vs[(c0 + j + 1) * LDK + trow] = v.y;
        Vs[(c0 + j + 2) * LDK + trow] = v.z;
        Vs[(c0 + j + 3) * LDK + trow] = v.w;
      }
    }
    __syncthreads();

    // S = (Q K^T) / 8
    f32x4 sfr[4];
#pragma unroll
    for (int kb = 0; kb < 4; kb++) {
      f32x4 sa = zero;
#pragma unroll
      for (int kk = 0; kk < 2; kk++) {
        u32 t[8];
        bf16x8 kh, kl;
        const u32* p = Ks + (kb * 16 + (l & 15)) * LDK + kk * 32 + ((l >> 4) << 3);
        *(uint4*)t = *(const uint4*)p;
        *(uint4*)(t + 4) = *(const uint4*)(p + 4);
        unpack8(t, kh, kl);
        sa = MFMA_BF16(ql[kk], kl, sa);
        sa = MFMA_BF16(ql[kk], kh, sa);
        sa = MFMA_BF16(qh[kk], kl, sa);
        sa = MFMA_BF16(qh[kk], kh, sa);
      }
      sfr[kb] = sa * 0.125f;
    }
    if (kt == qt) {  // diagonal tile: causal mask
#pragma unroll
      for (int kb = 0; kb < 4; kb++) {
        int t = kt * 64 + kb * 16 + (l & 15);
#pragma unroll
        for (int r = 0; r < 4; r++) {
          int qq = q0 + w * 16 + ((l >> 4) << 2) + r;
          if (t > qq) sfr[kb][r] = -3.0e38f;
        }
      }
    }
    // online softmax (rows distributed: row = (l>>4)*4+r, cols over lanes l&15)
#pragma unroll
    for (int r = 0; r < 4; r++) {
      float mx = fmaxf(fmaxf(sfr[0][r], sfr[1][r]), fmaxf(sfr[2][r], sfr[3][r]));
#pragma unroll
      for (int mm = 1; mm < 16; mm <<= 1) mx = fmaxf(mx, __shfl_xor(mx, mm));
      float mnew = fmaxf(mrun[r], mx);
      float sf = __expf(mrun[r] - mnew);
      mrun[r] = mnew;
      float rs = 0.f;
#pragma unroll
      for (int kb = 0; kb < 4; kb++) {
        float p = __expf(sfr[kb][r] - mnew);
        sfr[kb][r] = p;
        rs += p;
      }
#pragma unroll
      for (int mm = 1; mm < 16; mm <<= 1) rs += __shfl_xor(rs, mm);
      lrun[r] = lrun[r] * sf + rs;
#pragma unroll
      for (int vb = 0; vb < 4; vb++) oacc[vb][r] *= sf;
    }
    // write P (hi/lo packed) to per-wave LDS region
#pragma unroll
    for (int kb = 0; kb < 4; kb++)
#pragma unroll
      for (int r = 0; r < 4; r++)
        Ps[(w * 16 + ((l >> 4) << 2) + r) * LDK + kb * 16 + (l & 15)] = pack_hl(sfr[kb][r]);
    // PV (same-wave LDS RAW: compiler inserts lgkmcnt wait)
#pragma unroll
    for (int ks = 0; ks < 2; ks++) {
      bf16x8 ph, pl;
      {
        u32 t[8];
        const u32* pp = Ps + (w * 16 + (l & 15)) * LDK + ks * 32 + ((l >> 4) << 3);
        *(uint4*)t = *(const uint4*)pp;
        *(uint4*)(t + 4) = *(const uint4*)(pp + 4);
        unpack8(t, ph, pl);
      }
#pragma unroll
      for (int vb = 0; vb < 4; vb++) {
        u32 t2[8];
        bf16x8 vh, vl;
        const u32* pv = Vs + (vb * 16 + (l & 15)) * LDK + ks * 32 + ((l >> 4) << 3);
        *(uint4*)t2 = *(const uint4*)pv;
        *(uint4*)(t2 + 4) = *(const uint4*)(pv + 4);
        unpack8(t2, vh, vl);
        f32x4 c = oacc[vb];
        c = MFMA_BF16(pl, vl, c);
        c = MFMA_BF16(pl, vh, c);
        c = MFMA_BF16(ph, vl, c);
        c = MFMA_BF16(ph, vh, c);
        oacc[vb] = c;
      }
    }
  }
  // epilogue: ctx = oacc / l, packed hi/lo
#pragma unroll
  for (int vb = 0; vb < 4; vb++)
#pragma unroll
    for (int r = 0; r < 4; r++) {
      float o = oacc[vb][r] / lrun[r];
      int row = q0 + w * 16 + ((l >> 4) << 2) + r;
      int col = hc + vb * 16 + (l & 15);
      Op[(size_t)row * kD + col] = pack_hl(o);
    }
}

// ---------- router: f32 logits, softmax -> d_out, top-2 (order on exact f32 logits) ----------
__global__ __launch_bounds__(256) void router_kernel(
    const float* __restrict__ normed, const float* __restrict__ Wg,
    float* __restrict__ probs, float* __restrict__ gates,
    int* __restrict__ experts, int* __restrict__ counts) {
  const int w = threadIdx.x >> 6, l = threadIdx.x & 63;
  const int s = blockIdx.x * 4 + w;
  float lg[kE];
  const float* row = normed + (size_t)s * kD;
#pragma unroll
  for (int e = 0; e < kE; e++) {
    const float* wg = Wg + (size_t)e * kD;
    float a = 0.f;
    for (int d = l; d < kD; d += 64) a += row[d] * wg[d];
#pragma unroll
    for (int m = 32; m; m >>= 1) a += __shfl_xor(a, m);
    lg[e] = a;
  }
  if (l == 0) {
    float mx = lg[0];
#pragma unroll
    for (int e = 1; e < kE; e++) mx = fmaxf(mx, lg[e]);
    float p[kE], sum = 0.f;
#pragma unroll
    for (int e = 0; e < kE; e++) { p[e] = __expf(lg[e] - mx); sum += p[e]; }
    float inv = 1.f / sum;
#pragma unroll
    for (int e = 0; e < kE; e++) { p[e] *= inv; probs[(size_t)s * kE + e] = p[e]; }
    int i1 = 0;
#pragma unroll
    for (int e = 1; e < kE; e++) if (lg[e] > lg[i1]) i1 = e;
    int i2 = (i1 == 0) ? 1 : 0;
#pragma unroll
    for (int e = 0; e < kE; e++) if (e != i1 && lg[e] > lg[i2]) i2 = e;
    float den = 1.f / (p[i1] + p[i2]);
    gates[s * 2] = p[i1] * den;
    gates[s * 2 + 1] = p[i2] * den;
    experts[s * 2] = i1;
    experts[s * 2 + 1] = i2;
    atomicAdd(&counts[i1], 1);
    atomicAdd(&counts[i2], 1);
  }
}

__global__ void moe_init(int* counts) {
  if (threadIdx.x < kE) counts[threadIdx.x] = 0;
}
__global__ void moe_scan(const int* __restrict__ counts, int* __restrict__ ebase,
                         int* __restrict__ cursor) {
  if (threadIdx.x == 0) {
    int acc = 0;
    for (int e = 0; e < kE; e++) { ebase[e] = acc; cursor[e] = acc; acc += counts[e]; }
    ebase[kE] = acc;
  }
}
__global__ void moe_fill(const int* __restrict__ experts, int* __restrict__ cursor,
                         int* __restrict__ slot_list, int* __restrict__ slot_of) {
  int s = blockIdx.x * 256 + threadIdx.x;
  if (s >= kS) return;
  for (int k = 0; k < 2; k++) {
    int e = experts[s * 2 + k];
    int pos = atomicAdd(&cursor[e], 1);
    slot_list[pos] = s;
    slot_of[s * 2 + k] = pos;
  }
}

// ---------- grouped MoE GEMM: C[m,n] = sum_k A[row(m),k] * B[e][n,k] (bf16 MFMA) ----------
// MODE 0: write u (bf16). MODE 1: write hidden = gelu(u)*val in-place (bf16). MODE 2: write f32.
template <int MODE>
__global__ __launch_bounds__(256) void gemm_moe(
    const u16* __restrict__ A, const float* __restrict__ B, size_t strideB,
    const int* __restrict__ slot_list, const int* __restrict__ ebase,
    int N, int K, int gather, u16* __restrict__ U, float* __restrict__ Cf) {
  const int e = blockIdx.z;
  const int base = ebase[e];
  const int Me = ebase[e + 1] - base;
  const int m0 = blockIdx.y * 128;
  if (m0 >= Me) return;
  const int n0 = blockIdx.x * 128;
  constexpr int LDT = 40;  // padded bf16 stride (80B)
  __shared__ u16 Asb[128 * LDT];
  __shared__ u16 Bsb[128 * LDT];
  const int tid = threadIdx.x;
  const int w = tid >> 6, l = tid & 63;
  const int wr = (w >> 1) * 64, wc = (w & 1) * 64;
  f32x4 zero = {0.f, 0.f, 0.f, 0.f};
  f32x4 acc[4][4];
#pragma unroll
  for (int i = 0; i < 4; i++)
#pragma unroll
    for (int j = 0; j < 4; j++) acc[i][j] = zero;

  const int srow = tid >> 1, scol = (tid & 1) * 16;
  int mrow = m0 + srow;
  if (mrow > Me - 1) mrow = Me - 1;
  const int arow = gather ? slot_list[base + mrow] : (base + mrow);
  const u16* ga = A + (size_t)arow * K + scol;
  const float* gb = B + strideB * e + (size_t)(n0 + srow) * K + scol;
  u16* sa = Asb + srow * LDT + scol;
  u16* sb = Bsb + srow * LDT + scol;

  for (int k0 = 0; k0 < K; k0 += 32) {
    uint4 av0 = *(const uint4*)(ga + k0);
    uint4 av1 = *(const uint4*)(ga + k0 + 8);
    float4 f0 = *(const float4*)(gb + k0);
    float4 f1 = *(const float4*)(gb + k0 + 4);
    float4 f2 = *(const float4*)(gb + k0 + 8);
    float4 f3 = *(const float4*)(gb + k0 + 12);
    u32 pk[8];
    pk[0] = ((u32)bf16_rne(f0.y) << 16) | bf16_rne(f0.x);
    pk[1] = ((u32)bf16_rne(f0.w) << 16) | bf16_rne(f0.z);
    pk[2] = ((u32)bf16_rne(f1.y) << 16) | bf16_rne(f1.x);
    pk[3] = ((u32)bf16_rne(f1.w) << 16) | bf16_rne(f1.z);
    pk[4] = ((u32)bf16_rne(f2.y) << 16) | bf16_rne(f2.x);
    pk[5] = ((u32)bf16_rne(f2.w) << 16) | bf16_rne(f2.z);
    pk[6] = ((u32)bf16_rne(f3.y) << 16) | bf16_rne(f3.x);
    pk[7] = ((u32)bf16_rne(f3.w) << 16) | bf16_rne(f3.z);
    __syncthreads();
    *(uint4*)sa = av0;
    *(uint4*)(sa + 8) = av1;
    *(uint4*)sb = *(uint4*)(pk);
    *(uint4*)(sb + 8) = *(uint4*)(pk + 4);
    __syncthreads();

    bf16x8 af[4], bfr[4];
#pragma unroll
    for (int i = 0; i < 4; i++) {
      af[i] = *(const bf16x8*)(Asb + (wr + i * 16 + (l & 15)) * LDT + ((l >> 4) << 3));
      bfr[i] = *(const bf16x8*)(Bsb + (wc + i * 16 + (l & 15)) * LDT + ((l >> 4) << 3));
    }
#pragma unroll
    for (int mi = 0; mi < 4; mi++)
#pragma unroll
      for (int ni = 0; ni < 4; ni++) acc[mi][ni] = MFMA_BF16(af[mi], bfr[ni], acc[mi][ni]);
  }
#pragma unroll
  for (int mi = 0; mi < 4; mi++)
#pragma unroll
    for (int r = 0; r < 4; r++) {
      int ml = m0 + wr + mi * 16 + ((l >> 4) << 2) + r;
      if (ml >= Me) continue;
      size_t rb = (size_t)(base + ml) * N;
#pragma unroll
      for (int ni = 0; ni < 4; ni++) {
        int col = n0 + wc + ni * 16 + (l & 15);
        float a = acc[mi][ni][r];
        if (MODE == 0) {
          U[rb + col] = bf16_rne(a);
        } else if (MODE == 1) {
          float u = bf16_f32(U[rb + col]);
          float g = 0.5f * u * (1.0f + erff(u * 0.70710678118654752f));
          U[rb + col] = bf16_rne(g * a);
        } else {
          Cf[rb + col] = a;
        }
      }
    }
}

// ---------- final combine: out = h + g0*eo[p0] + g1*eo[p1] ----------
__global__ __launch_bounds__(256) void combine_kernel(
    const float* __restrict__ h, const float* __restrict__ eo,
    const float* __restrict__ gates, const int* __restrict__ slot_of,
    float* __restrict__ out) {
  const int s = blockIdx.x;
  const float g0 = gates[s * 2], g1 = gates[s * 2 + 1];
  const int p0 = slot_of[s * 2], p1 = slot_of[s * 2 + 1];
  const int c = threadIdx.x * 4;
  float4 hv = *(const float4*)(h + (size_t)s * kD + c);
  float4 e0 = *(const float4*)(eo + (size_t)p0 * kD + c);
  float4 e1 = *(const float4*)(eo + (size_t)p1 * kD + c);
  float4 o;
  o.x = hv.x + g0 * e0.x + g1 * e1.x;
  o.y = hv.y + g0 * e0.y + g1 * e1.y;
  o.z = hv.z + g0 * e0.z + g1 * e1.z;
  o.w = hv.w + g0 * e0.w + g1 * e1.w;
  *(float4*)(out + (size_t)s * kD + c) = o;
}

extern "C" void kernel_launch(void* const* d_in, const int* in_sizes, int n_in,
                              void* d_out, int out_size, void* d_ws, size_t ws_size,
                              hipStream_t stream) {
  (void)in_sizes; (void)n_in; (void)out_size; (void)ws_size;
  const float* x = (const float*)d_in[0];
  // d_in[1]: causal mask (tril) — causality applied analytically
  const float* scale_attn = (const float*)d_in[2];
  const float* Wq = (const float*)d_in[3];
  const float* Wk = (const float*)d_in[4];
  const float* Wv = (const float*)d_in[5];
  const float* Wo = (const float*)d_in[6];
  const float* scale_ffn = (const float*)d_in[7];
  const float* Wg = (const float*)d_in[8];
  const float* W_in = (const float*)d_in[9];
  const float* W_vv = (const float*)d_in[10];
  const float* W_out = (const float*)d_in[11];
  float* out = (float*)d_out;
  float* probs = out + (size_t)kS * kD;

  char* wsb = (char*)d_ws;
  size_t off = 0;
  auto alloc = [&](size_t bytes) -> void* {
    void* p = wsb + off;
    off += (bytes + 255) & ~(size_t)255;
    return p;
  };
  const size_t SDu = (size_t)kS * kD;
  u32* normA = (u32*)alloc(SDu * 4);
  u32* qpk = (u32*)alloc(SDu * 4);
  u32* kpk = (u32*)alloc(SDu * 4);
  u32* vpk = (u32*)alloc(SDu * 4);
  u32* ctxpk = (u32*)alloc(SDu * 4);
  float* h = (float*)alloc(SDu * 4);
  float* normFf = (float*)alloc(SDu * 4);
  u16* normFb = (u16*)alloc(SDu * 2);
  u32* Wqpk = (u32*)alloc((size_t)kD * kD * 4);
  u32* Wkpk = (u32*)alloc((size_t)kD * kD * 4);
  u32* Wvpk = (u32*)alloc((size_t)kD * kD * 4);
  u32* Wopk = (u32*)alloc((size_t)kD * kD * 4);
  u16* U = (u16*)alloc((size_t)kSlots * kFF * 2);
  float* eo = (float*)alloc((size_t)kSlots * kD * 4);
  float* gates = (float*)alloc(kS * 2 * 4);
  int* experts = (int*)alloc(kS * 2 * 4);
  int* slot_of = (int*)alloc(kS * 2 * 4);
  int* slot_list = (int*)alloc(kSlots * 4);
  int* counts = (int*)alloc(64);
  int* ebase = (int*)alloc(64);
  int* cursor = (int*)alloc(64);

  const int nW = kD * kD;
  pack_kernel<<<(nW + 255) / 256, 256, 0, stream>>>(Wq, Wqpk, nW);
  pack_kernel<<<(nW + 255) / 256, 256, 0, stream>>>(Wk, Wkpk, nW);
  pack_kernel<<<(nW + 255) / 256, 256, 0, stream>>>(Wv, Wvpk, nW);
  pack_kernel<<<(nW + 255) / 256, 256, 0, stream>>>(Wo, Wopk, nW);

  rmsnorm_kernel<0><<<kS, 256, 0, stream>>>(x, scale_attn, normA, nullptr, nullptr);
  dim3 gqkv(kD / 128, kS / 128);
  gemm_split<0><<<gqkv, 256, 0, stream>>>(normA, Wqpk, kS, kD, kD, qpk, nullptr, nullptr);
  gemm_split<0><<<gqkv, 256, 0, stream>>>(normA, Wkpk, kS, kD, kD, kpk, nullptr, nullptr);
  gemm_split<0><<<gqkv, 256, 0, stream>>>(normA, Wvpk, kS, kD, kD, vpk, nullptr, nullptr);
  attn_kernel<<<dim3(kS / 64, kH), 256, 0, stream>>>(qpk, kpk, vpk, ctxpk);
  gemm_split<1><<<gqkv, 256, 0, stream>>>(ctxpk, Wopk, kS, kD, kD, nullptr, x, h);

  rmsnorm_kernel<1><<<kS, 256, 0, stream>>>(h, scale_ffn, nullptr, normFf, normFb);
  moe_init<<<1, 64, 0, stream>>>(counts);
  router_kernel<<<kS / 4, 256, 0, stream>>>(normFf, Wg, probs, gates, experts, counts);
  moe_scan<<<1, 64, 0, stream>>>(counts, ebase, cursor);
  moe_fill<<<kS / 256, 256, 0, stream>>>(experts, cursor, slot_list, slot_of);

  gemm_moe<0><<<dim3(kFF / 128, kSlots / 128, kE), 256, 0, stream>>>(
      normFb, W_in, (size_t)kFF * kD, slot_list, ebase, kFF, kD, 1, U, nullptr);
  gemm_moe<1><<<dim3(kFF / 128, kSlots / 128, kE), 256, 0, stream>>>(
      normFb, W_vv, (size_t)kFF * kD, slot_list, ebase, kFF, kD, 1, U, nullptr);
  gemm_moe<2><<<dim3(kD / 128, kSlots / 128, kE), 256, 0, stream>>>(
      U, W_out, (size_t)kD * kFF, slot_list, ebase, kD, kFF, 0, U, eo);

  combine_kernel<<<kS, 256, 0, stream>>>(h, eo, gates, slot_of, out);
}

// Round 2
// 918.750 us; speedup vs baseline: 1.0826x; 1.0826x over previous
//
#include <hip/hip_runtime.h>
#include <hip/hip_bf16.h>
#include <math.h>

typedef unsigned int u32;
typedef unsigned short u16;
using bf16x8 = __attribute__((ext_vector_type(8))) short;
using f32x4 = __attribute__((ext_vector_type(4))) float;

#define MFMA_BF16(a, b, c) __builtin_amdgcn_mfma_f32_16x16x32_bf16((a), (b), (c), 0, 0, 0)

constexpr int kS = 2048, kD = 1024, kH = 16, kE = 8, kFF = 4096;
constexpr int kSlots = kS * 2;  // 4096 (token, expert) slots, top-2 routing

// ---------- numeric helpers ----------
__device__ __forceinline__ u16 bf16_rne(float f) {
  u32 u = __float_as_uint(f);
  u32 r = (u + 0x7fffu + ((u >> 16) & 1u)) >> 16;
  return (u16)r;
}
__device__ __forceinline__ float bf16_f32(u16 h) { return __uint_as_float(((u32)h) << 16); }
// pack f32 as hi/lo bf16 pair in one u32 (lo16 bits = hi part, hi16 bits = lo part)
__device__ __forceinline__ u32 pack_hl(float x) {
  u16 hi = bf16_rne(x);
  u16 lo = bf16_rne(x - bf16_f32(hi));
  return ((u32)lo << 16) | (u32)hi;
}
__device__ __forceinline__ void unpack8(const u32* t, bf16x8& h, bf16x8& l) {
#pragma unroll
  for (int j = 0; j < 8; j++) {
    h[j] = (short)(t[j] & 0xffffu);
    l[j] = (short)(t[j] >> 16);
  }
}
__device__ __forceinline__ void gload_lds16(const void* g, void* l) {
  __builtin_amdgcn_global_load_lds((const __attribute__((address_space(1))) u32*)g,
                                   (__attribute__((address_space(3))) u32*)l, 16, 0, 0);
}

// ---------- weight hi/lo split (attention path) ----------
__global__ void pack_kernel(const float* __restrict__ w, u32* __restrict__ o, int n) {
  int i = blockIdx.x * 256 + threadIdx.x;
  if (i < n) o[i] = pack_hl(w[i]);
}

// ---------- f32 -> bf16 pack, 8 elems/thread (MoE weights) ----------
__global__ __launch_bounds__(256) void pack_bf16_kernel(const float* __restrict__ w,
                                                        u16* __restrict__ o, int n8) {
  int i = blockIdx.x * 256 + threadIdx.x;
  if (i >= n8) return;
  const float4* s = (const float4*)w + (size_t)i * 2;
  float4 a = s[0], b = s[1];
  u16 r[8] = {bf16_rne(a.x), bf16_rne(a.y), bf16_rne(a.z), bf16_rne(a.w),
              bf16_rne(b.x), bf16_rne(b.y), bf16_rne(b.z), bf16_rne(b.w)};
  *(uint4*)(o + (size_t)i * 8) = *(uint4*)r;
}

// ---------- RMSNorm (f32-exact). MODE 0: write packed hi/lo. MODE 1: write f32 + bf16 ----------
template <int MODE>
__global__ __launch_bounds__(256) void rmsnorm_kernel(
    const float* __restrict__ x, const float* __restrict__ scale,
    u32* __restrict__ opk, float* __restrict__ of32, u16* __restrict__ ob16) {
  const int s = blockIdx.x;
  const float* row = x + (size_t)s * kD;
  const int c = threadIdx.x * 4;
  float4 v = *(const float4*)(row + c);
  float ss = v.x * v.x + v.y * v.y + v.z * v.z + v.w * v.w;
#pragma unroll
  for (int m = 32; m; m >>= 1) ss += __shfl_xor(ss, m);
  __shared__ float wsum[4];
  if ((threadIdx.x & 63) == 0) wsum[threadIdx.x >> 6] = ss;
  __syncthreads();
  float tot = wsum[0] + wsum[1] + wsum[2] + wsum[3];
  float rinv = 1.0f / sqrtf(tot * (1.0f / kD) + 1e-5f);
  float4 sc = *(const float4*)(scale + c);
  float n0 = v.x * rinv * sc.x, n1 = v.y * rinv * sc.y;
  float n2 = v.z * rinv * sc.z, n3 = v.w * rinv * sc.w;
  if (MODE == 0) {
    u32* o = opk + (size_t)s * kD + c;
    o[0] = pack_hl(n0); o[1] = pack_hl(n1); o[2] = pack_hl(n2); o[3] = pack_hl(n3);
  } else {
    *(float4*)(of32 + (size_t)s * kD + c) = make_float4(n0, n1, n2, n3);
    u16* o = ob16 + (size_t)s * kD + c;
    o[0] = bf16_rne(n0); o[1] = bf16_rne(n1); o[2] = bf16_rne(n2); o[3] = bf16_rne(n3);
  }
}

// ---------- split-bf16 4-term GEMM (attention path, ~f32 precision) ----------
template <int MODE>
__global__ __launch_bounds__(256) void gemm_split(
    const u32* __restrict__ A, const u32* __restrict__ B, int M, int N, int K,
    u32* __restrict__ Cpk, const float* __restrict__ resid, float* __restrict__ Cf) {
  constexpr int LDT = 36;
  __shared__ u32 As[128 * LDT];
  __shared__ u32 Bs[128 * LDT];
  const int tid = threadIdx.x;
  const int w = tid >> 6, l = tid & 63;
  const int m0 = blockIdx.y * 128, n0 = blockIdx.x * 128;
  const int wr = (w >> 1) * 64, wc = (w & 1) * 64;
  f32x4 zero = {0.f, 0.f, 0.f, 0.f};
  f32x4 acc[4][4];
#pragma unroll
  for (int i = 0; i < 4; i++)
#pragma unroll
    for (int j = 0; j < 4; j++) acc[i][j] = zero;

  const int srow = tid >> 1, scol = (tid & 1) * 16;
  const u32* gA = A + (size_t)(m0 + srow) * K + scol;
  const u32* gB = B + (size_t)(n0 + srow) * K + scol;
  u32* sA = As + srow * LDT + scol;
  u32* sB = Bs + srow * LDT + scol;

  for (int k0 = 0; k0 < K; k0 += 32) {
    uint4 a0 = *(const uint4*)(gA + k0);
    uint4 a1 = *(const uint4*)(gA + k0 + 4);
    uint4 a2 = *(const uint4*)(gA + k0 + 8);
    uint4 a3 = *(const uint4*)(gA + k0 + 12);
    uint4 b0 = *(const uint4*)(gB + k0);
    uint4 b1 = *(const uint4*)(gB + k0 + 4);
    uint4 b2 = *(const uint4*)(gB + k0 + 8);
    uint4 b3 = *(const uint4*)(gB + k0 + 12);
    __syncthreads();
    *(uint4*)(sA) = a0; *(uint4*)(sA + 4) = a1; *(uint4*)(sA + 8) = a2; *(uint4*)(sA + 12) = a3;
    *(uint4*)(sB) = b0; *(uint4*)(sB + 4) = b1; *(uint4*)(sB + 8) = b2; *(uint4*)(sB + 12) = b3;
    __syncthreads();

    bf16x8 ah[4], al[4], bh[4], bl[4];
#pragma unroll
    for (int i = 0; i < 4; i++) {
      u32 t[8];
      const u32* pa = As + (wr + i * 16 + (l & 15)) * LDT + ((l >> 4) << 3);
      *(uint4*)t = *(const uint4*)pa;
      *(uint4*)(t + 4) = *(const uint4*)(pa + 4);
      unpack8(t, ah[i], al[i]);
      const u32* pb = Bs + (wc + i * 16 + (l & 15)) * LDT + ((l >> 4) << 3);
      *(uint4*)t = *(const uint4*)pb;
      *(uint4*)(t + 4) = *(const uint4*)(pb + 4);
      unpack8(t, bh[i], bl[i]);
    }
#pragma unroll
    for (int mi = 0; mi < 4; mi++)
#pragma unroll
      for (int ni = 0; ni < 4; ni++) {
        f32x4 c = acc[mi][ni];
        c = MFMA_BF16(al[mi], bl[ni], c);
        c = MFMA_BF16(al[mi], bh[ni], c);
        c = MFMA_BF16(ah[mi], bl[ni], c);
        c = MFMA_BF16(ah[mi], bh[ni], c);
        acc[mi][ni] = c;
      }
  }
#pragma unroll
  for (int mi = 0; mi < 4; mi++)
#pragma unroll
    for (int ni = 0; ni < 4; ni++)
#pragma unroll
      for (int r = 0; r < 4; r++) {
        int row = m0 + wr + mi * 16 + ((l >> 4) << 2) + r;
        int col = n0 + wc + ni * 16 + (l & 15);
        float v = acc[mi][ni][r];
        if (MODE == 0) Cpk[(size_t)row * N + col] = pack_hl(v);
        else Cf[(size_t)row * N + col] = resid[(size_t)row * N + col] + v;
      }
}

// ---------- flash attention, causal, split-bf16 4-term, ~f32 precision ----------
__global__ __launch_bounds__(256) void attn_kernel(
    const u32* __restrict__ Qp, const u32* __restrict__ Kp, const u32* __restrict__ Vp,
    u32* __restrict__ Op) {
  constexpr int LDK = 68;
  __shared__ u32 Ks[64 * LDK];
  __shared__ u32 Vs[64 * LDK];
  __shared__ u32 Ps[64 * LDK];
  const int tid = threadIdx.x, w = tid >> 6, l = tid & 63;
  const int qt = blockIdx.x, hh = blockIdx.y;
  const int q0 = qt * 64, hc = hh * 64;

  bf16x8 qh[2], ql[2];
  {
    const int qrow = q0 + w * 16 + (l & 15);
#pragma unroll
    for (int kk = 0; kk < 2; kk++) {
      u32 t[8];
      const u32* p = Qp + (size_t)qrow * kD + hc + kk * 32 + ((l >> 4) << 3);
      *(uint4*)t = *(const uint4*)p;
      *(uint4*)(t + 4) = *(const uint4*)(p + 4);
      unpack8(t, qh[kk], ql[kk]);
    }
  }
  float mrun[4], lrun[4];
  f32x4 zero = {0.f, 0.f, 0.f, 0.f};
  f32x4 oacc[4];
#pragma unroll
  for (int r = 0; r < 4; r++) { mrun[r] = -3.0e38f; lrun[r] = 0.f; }
#pragma unroll
  for (int vb = 0; vb < 4; vb++) oacc[vb] = zero;

  for (int kt = 0; kt <= qt; kt++) {
    __syncthreads();
    {
      const int trow = tid >> 2, c0 = (tid & 3) * 16;
      const u32* gK = Kp + (size_t)(kt * 64 + trow) * kD + hc + c0;
      u32* sK = Ks + trow * LDK + c0;
      *(uint4*)sK = *(const uint4*)gK;
      *(uint4*)(sK + 4) = *(const uint4*)(gK + 4);
      *(uint4*)(sK + 8) = *(const uint4*)(gK + 8);
      *(uint4*)(sK + 12) = *(const uint4*)(gK + 12);
      const u32* gV = Vp + (size_t)(kt * 64 + trow) * kD + hc + c0;
#pragma unroll
      for (int j = 0; j < 16; j += 4) {
        uint4 v = *(const uint4*)(gV + j);
        Vs[(c0 + j + 0) * LDK + trow] = v.x;
        Vs[(c0 + j + 1) * LDK + trow] = v.y;
        Vs[(c0 + j + 2) * LDK + trow] = v.z;
        Vs[(c0 + j + 3) * LDK + trow] = v.w;
      }
    }
    __syncthreads();

    f32x4 sfr[4];
#pragma unroll
    for (int kb = 0; kb < 4; kb++) {
      f32x4 sa = zero;
#pragma unroll
      for (int kk = 0; kk < 2; kk++) {
        u32 t[8];
        bf16x8 kh, kl;
        const u32* p = Ks + (kb * 16 + (l & 15)) * LDK + kk * 32 + ((l >> 4) << 3);
        *(uint4*)t = *(const uint4*)p;
        *(uint4*)(t + 4) = *(const uint4*)(p + 4);
        unpack8(t, kh, kl);
        sa = MFMA_BF16(ql[kk], kl, sa);
        sa = MFMA_BF16(ql[kk], kh, sa);
        sa = MFMA_BF16(qh[kk], kl, sa);
        sa = MFMA_BF16(qh[kk], kh, sa);
      }
      sfr[kb] = sa * 0.125f;
    }
    if (kt == qt) {
#pragma unroll
      for (int kb = 0; kb < 4; kb++) {
        int t = kt * 64 + kb * 16 + (l & 15);
#pragma unroll
        for (int r = 0; r < 4; r++) {
          int qq = q0 + w * 16 + ((l >> 4) << 2) + r;
          if (t > qq) sfr[kb][r] = -3.0e38f;
        }
      }
    }
#pragma unroll
    for (int r = 0; r < 4; r++) {
      float mx = fmaxf(fmaxf(sfr[0][r], sfr[1][r]), fmaxf(sfr[2][r], sfr[3][r]));
#pragma unroll
      for (int mm = 1; mm < 16; mm <<= 1) mx = fmaxf(mx, __shfl_xor(mx, mm));
      float mnew = fmaxf(mrun[r], mx);
      float sf = __expf(mrun[r] - mnew);
      mrun[r] = mnew;
      float rs = 0.f;
#pragma unroll
      for (int kb = 0; kb < 4; kb++) {
        float p = __expf(sfr[kb][r] - mnew);
        sfr[kb][r] = p;
        rs += p;
      }
#pragma unroll
      for (int mm = 1; mm < 16; mm <<= 1) rs += __shfl_xor(rs, mm);
      lrun[r] = lrun[r] * sf + rs;
#pragma unroll
      for (int vb = 0; vb < 4; vb++) oacc[vb][r] *= sf;
    }
#pragma unroll
    for (int kb = 0; kb < 4; kb++)
#pragma unroll
      for (int r = 0; r < 4; r++)
        Ps[(w * 16 + ((l >> 4) << 2) + r) * LDK + kb * 16 + (l & 15)] = pack_hl(sfr[kb][r]);
#pragma unroll
    for (int ks = 0; ks < 2; ks++) {
      bf16x8 ph, pl;
      {
        u32 t[8];
        const u32* pp = Ps + (w * 16 + (l & 15)) * LDK + ks * 32 + ((l >> 4) << 3);
        *(uint4*)t = *(const uint4*)pp;
        *(uint4*)(t + 4) = *(const uint4*)(pp + 4);
        unpack8(t, ph, pl);
      }
#pragma unroll
      for (int vb = 0; vb < 4; vb++) {
        u32 t2[8];
        bf16x8 vh, vl;
        const u32* pv = Vs + (vb * 16 + (l & 15)) * LDK + ks * 32 + ((l >> 4) << 3);
        *(uint4*)t2 = *(const uint4*)pv;
        *(uint4*)(t2 + 4) = *(const uint4*)(pv + 4);
        unpack8(t2, vh, vl);
        f32x4 c = oacc[vb];
        c = MFMA_BF16(pl, vl, c);
        c = MFMA_BF16(pl, vh, c);
        c = MFMA_BF16(ph, vl, c);
        c = MFMA_BF16(ph, vh, c);
        oacc[vb] = c;
      }
    }
  }
#pragma unroll
  for (int vb = 0; vb < 4; vb++)
#pragma unroll
    for (int r = 0; r < 4; r++) {
      float o = oacc[vb][r] / lrun[r];
      int row = q0 + w * 16 + ((l >> 4) << 2) + r;
      int col = hc + vb * 16 + (l & 15);
      Op[(size_t)row * kD + col] = pack_hl(o);
    }
}

// ---------- router ----------
__global__ __launch_bounds__(256) void router_kernel(
    const float* __restrict__ normed, const float* __restrict__ Wg,
    float* __restrict__ probs, float* __restrict__ gates,
    int* __restrict__ experts, int* __restrict__ counts) {
  const int w = threadIdx.x >> 6, l = threadIdx.x & 63;
  const int s = blockIdx.x * 4 + w;
  float lg[kE];
  const float* row = normed + (size_t)s * kD;
#pragma unroll
  for (int e = 0; e < kE; e++) {
    const float* wg = Wg + (size_t)e * kD;
    float a = 0.f;
    for (int d = l; d < kD; d += 64) a += row[d] * wg[d];
#pragma unroll
    for (int m = 32; m; m >>= 1) a += __shfl_xor(a, m);
    lg[e] = a;
  }
  if (l == 0) {
    float mx = lg[0];
#pragma unroll
    for (int e = 1; e < kE; e++) mx = fmaxf(mx, lg[e]);
    float p[kE], sum = 0.f;
#pragma unroll
    for (int e = 0; e < kE; e++) { p[e] = __expf(lg[e] - mx); sum += p[e]; }
    float inv = 1.f / sum;
#pragma unroll
    for (int e = 0; e < kE; e++) { p[e] *= inv; probs[(size_t)s * kE + e] = p[e]; }
    int i1 = 0;
#pragma unroll
    for (int e = 1; e < kE; e++) if (lg[e] > lg[i1]) i1 = e;
    int i2 = (i1 == 0) ? 1 : 0;
#pragma unroll
    for (int e = 0; e < kE; e++) if (e != i1 && lg[e] > lg[i2]) i2 = e;
    float den = 1.f / (p[i1] + p[i2]);
    gates[s * 2] = p[i1] * den;
    gates[s * 2 + 1] = p[i2] * den;
    experts[s * 2] = i1;
    experts[s * 2 + 1] = i2;
    atomicAdd(&counts[i1], 1);
    atomicAdd(&counts[i2], 1);
  }
}

__global__ void moe_init(int* counts) {
  if (threadIdx.x < kE) counts[threadIdx.x] = 0;
}
__global__ void moe_scan(const int* __restrict__ counts, int* __restrict__ ebase,
                         int* __restrict__ cursor) {
  if (threadIdx.x == 0) {
    int acc = 0;
    for (int e = 0; e < kE; e++) { ebase[e] = acc; cursor[e] = acc; acc += counts[e]; }
    ebase[kE] = acc;
  }
}
__global__ void moe_fill(const int* __restrict__ experts, int* __restrict__ cursor,
                         int* __restrict__ slot_list, int* __restrict__ slot_of) {
  int s = blockIdx.x * 256 + threadIdx.x;
  if (s >= kS) return;
  for (int k = 0; k < 2; k++) {
    int e = experts[s * 2 + k];
    int pos = atomicAdd(&cursor[e], 1);
    slot_list[pos] = s;
    slot_of[s * 2 + k] = pos;
  }
}

// ---------- grouped MoE GEMM, m97-structure: global_load_lds + XOR-swizzled LDS ----------
// FUSED=1: A=normFb gathered via slot_list, B1=W_in, B2=W_v (K=1024,N=4096);
//          epilogue U[slot][n] = bf16(gelu(u) * v)
// FUSED=0: A=U rows direct (K=4096,N=1024), B1=W_out; epilogue eo[slot][n] = f32 acc
// LDS layout: linear [128][64] bf16, col-block (8 elems) XOR-swizzled by (row&7).
// Source is pre-swizzled (m173): lane covers global col-block (l&7)^(l>>3), so
// global_load_lds's linear lane-order write lands the swizzle; ds_read applies same XOR.
template <int FUSED>
__global__ __launch_bounds__(256) void moe_mm(
    const u16* __restrict__ A, const u16* __restrict__ B1g, const u16* __restrict__ B2g,
    const int* __restrict__ slot_list, const int* __restrict__ ebase,
    int N, int K, u16* __restrict__ Uo, float* __restrict__ eo) {
  const int e = blockIdx.z;
  const int base = ebase[e];
  const int Me = ebase[e + 1] - base;
  const int m0 = blockIdx.y * 128;
  if (m0 >= Me) return;
  const int n0 = blockIdx.x * 128;
  __shared__ u16 As[128 * 64];
  __shared__ u16 Bs1[128 * 64];
  __shared__ u16 Bs2[FUSED ? 128 * 64 : 16];
  const int tid = threadIdx.x, w = tid >> 6, l = tid & 63;
  const int wr = (w >> 1) * 64, wc = (w & 1) * 64;
  const int lr = l >> 3;                     // sub-row 0..7 within the wave-issue chunk
  const int colOff = ((l & 7) ^ lr) * 8;     // pre-swizzled source column (elements)
  const u16* B1 = B1g + (size_t)e * N * K;
  const u16* B2 = FUSED ? (B2g + (size_t)e * N * K) : nullptr;

  size_t aoff[4], boff[4];
#pragma unroll
  for (int i = 0; i < 4; i++) {
    int r = (w * 4 + i) * 8 + lr;            // tile row this lane stages
    int mr = m0 + r;
    if (mr >= Me) mr = Me - 1;               // clamp; epilogue guards writes
    int ar = FUSED ? slot_list[base + mr] : (base + mr);
    aoff[i] = (size_t)ar * K + colOff;
    boff[i] = (size_t)(n0 + r) * K + colOff;
  }

  f32x4 zero = {0.f, 0.f, 0.f, 0.f};
  f32x4 acc1[4][4], acc2[4][4];
#pragma unroll
  for (int i = 0; i < 4; i++)
#pragma unroll
    for (int j = 0; j < 4; j++) { acc1[i][j] = zero; acc2[i][j] = zero; }

  for (int k0 = 0; k0 < K; k0 += 64) {
#pragma unroll
    for (int i = 0; i < 4; i++) {
      gload_lds16(A + aoff[i] + k0, &As[(w * 4 + i) * 512]);
      gload_lds16(B1 + boff[i] + k0, &Bs1[(w * 4 + i) * 512]);
      if (FUSED) gload_lds16(B2 + boff[i] + k0, &Bs2[(w * 4 + i) * 512]);
    }
    __syncthreads();  // compiler drains vmcnt(0) before s_barrier -> tiles visible
#pragma unroll
    for (int kk = 0; kk < 2; kk++) {
      const int g = kk * 4 + (l >> 4);       // global col-block 0..7
      bf16x8 af[4];
#pragma unroll
      for (int mi = 0; mi < 4; mi++) {
        int row = wr + mi * 16 + (l & 15);
        af[mi] = *(const bf16x8*)&As[row * 64 + ((g ^ (row & 7)) * 8)];
      }
#pragma unroll
      for (int ni = 0; ni < 4; ni++) {
        int brow = wc + ni * 16 + (l & 15);
        int bo = brow * 64 + ((g ^ (brow & 7)) * 8);
        bf16x8 b1 = *(const bf16x8*)&Bs1[bo];
#pragma unroll
        for (int mi = 0; mi < 4; mi++) acc1[mi][ni] = MFMA_BF16(af[mi], b1, acc1[mi][ni]);
        if (FUSED) {
          bf16x8 b2 = *(const bf16x8*)&Bs2[bo];
#pragma unroll
          for (int mi = 0; mi < 4; mi++) acc2[mi][ni] = MFMA_BF16(af[mi], b2, acc2[mi][ni]);
        }
      }
    }
    __syncthreads();  // all waves done reading before next overwrite
  }

#pragma unroll
  for (int mi = 0; mi < 4; mi++)
#pragma unroll
    for (int r = 0; r < 4; r++) {
      int ml = m0 + wr + mi * 16 + ((l >> 4) << 2) + r;
      if (ml >= Me) continue;
      size_t rb = (size_t)(base + ml) * N;
#pragma unroll
      for (int ni = 0; ni < 4; ni++) {
        int col = n0 + wc + ni * 16 + (l & 15);
        if (FUSED) {
          float u = acc1[mi][ni][r], v = acc2[mi][ni][r];
          float ge = 0.5f * u * (1.0f + erff(u * 0.70710678118654752f));
          Uo[rb + col] = bf16_rne(ge * v);
        } else {
          eo[rb + col] = acc1[mi][ni][r];
        }
      }
    }
}

// ---------- final combine: out = h + g0*eo[p0] + g1*eo[p1] ----------
__global__ __launch_bounds__(256) void combine_kernel(
    const float* __restrict__ h, const float* __restrict__ eo,
    const float* __restrict__ gates, const int* __restrict__ slot_of,
    float* __restrict__ out) {
  const int s = blockIdx.x;
  const float g0 = gates[s * 2], g1 = gates[s * 2 + 1];
  const int p0 = slot_of[s * 2], p1 = slot_of[s * 2 + 1];
  const int c = threadIdx.x * 4;
  float4 hv = *(const float4*)(h + (size_t)s * kD + c);
  float4 e0 = *(const float4*)(eo + (size_t)p0 * kD + c);
  float4 e1 = *(const float4*)(eo + (size_t)p1 * kD + c);
  float4 o;
  o.x = hv.x + g0 * e0.x + g1 * e1.x;
  o.y = hv.y + g0 * e0.y + g1 * e1.y;
  o.z = hv.z + g0 * e0.z + g1 * e1.z;
  o.w = hv.w + g0 * e0.w + g1 * e1.w;
  *(float4*)(out + (size_t)s * kD + c) = o;
}

extern "C" void kernel_launch(void* const* d_in, const int* in_sizes, int n_in,
                              void* d_out, int out_size, void* d_ws, size_t ws_size,
                              hipStream_t stream) {
  (void)in_sizes; (void)n_in; (void)out_size; (void)ws_size;
  const float* x = (const float*)d_in[0];
  const float* scale_attn = (const float*)d_in[2];
  const float* Wq = (const float*)d_in[3];
  const float* Wk = (const float*)d_in[4];
  const float* Wv = (const float*)d_in[5];
  const float* Wo = (const float*)d_in[6];
  const float* scale_ffn = (const float*)d_in[7];
  const float* Wg = (const float*)d_in[8];
  const float* W_in = (const float*)d_in[9];
  const float* W_vv = (const float*)d_in[10];
  const float* W_out = (const float*)d_in[11];
  float* out = (float*)d_out;
  float* probs = out + (size_t)kS * kD;

  char* wsb = (char*)d_ws;
  size_t off = 0;
  auto alloc = [&](size_t bytes) -> void* {
    void* p = wsb + off;
    off += (bytes + 255) & ~(size_t)255;
    return p;
  };
  const size_t SDu = (size_t)kS * kD;
  const size_t EW = (size_t)kE * kFF * kD;  // elems per expert-weight tensor
  u32* normA = (u32*)alloc(SDu * 4);
  u32* qpk = (u32*)alloc(SDu * 4);
  u32* kpk = (u32*)alloc(SDu * 4);
  u32* vpk = (u32*)alloc(SDu * 4);
  u32* ctxpk = (u32*)alloc(SDu * 4);
  float* h = (float*)alloc(SDu * 4);
  float* normFf = (float*)alloc(SDu * 4);
  u16* normFb = (u16*)alloc(SDu * 2);
  u32* Wqpk = (u32*)alloc((size_t)kD * kD * 4);
  u32* Wkpk = (u32*)alloc((size_t)kD * kD * 4);
  u32* Wvpk = (u32*)alloc((size_t)kD * kD * 4);
  u32* Wopk = (u32*)alloc((size_t)kD * kD * 4);
  u16* Win_bf = (u16*)alloc(EW * 2);
  u16* Wv_bf = (u16*)alloc(EW * 2);
  u16* Wout_bf = (u16*)alloc(EW * 2);
  u16* U = (u16*)alloc((size_t)kSlots * kFF * 2);
  float* eo = (float*)alloc((size_t)kSlots * kD * 4);
  float* gates = (float*)alloc(kS * 2 * 4);
  int* experts = (int*)alloc(kS * 2 * 4);
  int* slot_of = (int*)alloc(kS * 2 * 4);
  int* slot_list = (int*)alloc(kSlots * 4);
  int* counts = (int*)alloc(64);
  int* ebase = (int*)alloc(64);
  int* cursor = (int*)alloc(64);

  const int nW = kD * kD;
  pack_kernel<<<(nW + 255) / 256, 256, 0, stream>>>(Wq, Wqpk, nW);
  pack_kernel<<<(nW + 255) / 256, 256, 0, stream>>>(Wk, Wkpk, nW);
  pack_kernel<<<(nW + 255) / 256, 256, 0, stream>>>(Wv, Wvpk, nW);
  pack_kernel<<<(nW + 255) / 256, 256, 0, stream>>>(Wo, Wopk, nW);
  const int n8 = (int)(EW / 8);
  pack_bf16_kernel<<<(n8 + 255) / 256, 256, 0, stream>>>(W_in, Win_bf, n8);
  pack_bf16_kernel<<<(n8 + 255) / 256, 256, 0, stream>>>(W_vv, Wv_bf, n8);
  pack_bf16_kernel<<<(n8 + 255) / 256, 256, 0, stream>>>(W_out, Wout_bf, n8);

  rmsnorm_kernel<0><<<kS, 256, 0, stream>>>(x, scale_attn, normA, nullptr, nullptr);
  dim3 gqkv(kD / 128, kS / 128);
  gemm_split<0><<<gqkv, 256, 0, stream>>>(normA, Wqpk, kS, kD, kD, qpk, nullptr, nullptr);
  gemm_split<0><<<gqkv, 256, 0, stream>>>(normA, Wkpk, kS, kD, kD, kpk, nullptr, nullptr);
  gemm_split<0><<<gqkv, 256, 0, stream>>>(normA, Wvpk, kS, kD, kD, vpk, nullptr, nullptr);
  attn_kernel<<<dim3(kS / 64, kH), 256, 0, stream>>>(qpk, kpk, vpk, ctxpk);
  gemm_split<1><<<gqkv, 256, 0, stream>>>(ctxpk, Wopk, kS, kD, kD, nullptr, x, h);

  rmsnorm_kernel<1><<<kS, 256, 0, stream>>>(h, scale_ffn, nullptr, normFf, normFb);
  moe_init<<<1, 64, 0, stream>>>(counts);
  router_kernel<<<kS / 4, 256, 0, stream>>>(normFf, Wg, probs, gates, experts, counts);
  moe_scan<<<1, 64, 0, stream>>>(counts, ebase, cursor);
  moe_fill<<<kS / 256, 256, 0, stream>>>(experts, cursor, slot_list, slot_of);

  moe_mm<1><<<dim3(kFF / 128, kSlots / 128, kE), 256, 0, stream>>>(
      normFb, Win_bf, Wv_bf, slot_list, ebase, kFF, kD, U, nullptr);
  moe_mm<0><<<dim3(kD / 128, kSlots / 128, kE), 256, 0, stream>>>(
      U, Wout_bf, nullptr, slot_list, ebase, kD, kFF, nullptr, eo);

  combine_kernel<<<kS, 256, 0, stream>>>(h, eo, gates, slot_of, out);
}

// Round 3
// 712.637 us; speedup vs baseline: 1.3957x; 1.2892x over previous
//
#include <hip/hip_runtime.h>
#include <hip/hip_bf16.h>
#include <math.h>

typedef unsigned int u32;
typedef unsigned short u16;
using bf16x8 = __attribute__((ext_vector_type(8))) short;
using f32x4 = __attribute__((ext_vector_type(4))) float;

#define MFMA_BF16(a, b, c) __builtin_amdgcn_mfma_f32_16x16x32_bf16((a), (b), (c), 0, 0, 0)

constexpr int kS = 2048, kD = 1024, kH = 16, kE = 8, kFF = 4096;
constexpr int kSlots = kS * 2;

// ---------- numeric helpers ----------
__device__ __forceinline__ u16 bf16_rne(float f) {
  u32 u = __float_as_uint(f);
  u32 r = (u + 0x7fffu + ((u >> 16) & 1u)) >> 16;
  return (u16)r;
}
__device__ __forceinline__ float bf16_f32(u16 h) { return __uint_as_float(((u32)h) << 16); }
__device__ __forceinline__ u32 pack_hl(float x) {
  u16 hi = bf16_rne(x);
  u16 lo = bf16_rne(x - bf16_f32(hi));
  return ((u32)lo << 16) | (u32)hi;
}
__device__ __forceinline__ void unpack8(const u32* t, bf16x8& h, bf16x8& l) {
#pragma unroll
  for (int j = 0; j < 8; j++) {
    h[j] = (short)(t[j] & 0xffffu);
    l[j] = (short)(t[j] >> 16);
  }
}
__device__ __forceinline__ void gload_lds16(const void* g, void* l) {
  __builtin_amdgcn_global_load_lds((const __attribute__((address_space(1))) u32*)g,
                                   (__attribute__((address_space(3))) u32*)l, 16, 0, 0);
}

// ---------- weight packs ----------
// dual-plane: row n, K chunked by 32: chunk c -> dpcols [c*64, c*64+32)=hi, [+32,+64)=lo
__global__ __launch_bounds__(256) void pack_dp3(const float* __restrict__ Wq,
                                                const float* __restrict__ Wk,
                                                const float* __restrict__ Wv,
                                                u16* __restrict__ o) {
  int i = blockIdx.x * 256 + threadIdx.x;
  if (i >= 3072 * 1024) return;
  int n = i >> 10, k = i & 1023;
  float v = (n < 1024) ? Wq[i] : (n < 2048) ? Wk[i - 1024 * 1024] : Wv[i - 2048 * 1024];
  u16 hi = bf16_rne(v);
  u16 lo = bf16_rne(v - bf16_f32(hi));
  size_t b = (size_t)n * 2048 + (size_t)(k >> 5) * 64 + (k & 31);
  o[b] = hi;
  o[b + 32] = lo;
}
__global__ __launch_bounds__(256) void pack_dp1(const float* __restrict__ W,
                                                u16* __restrict__ o, int n_elem) {
  int i = blockIdx.x * 256 + threadIdx.x;
  if (i >= n_elem) return;
  int k = i & 1023, n = i >> 10;
  float v = W[i];
  u16 hi = bf16_rne(v);
  u16 lo = bf16_rne(v - bf16_f32(hi));
  size_t b = (size_t)n * 2048 + (size_t)(k >> 5) * 64 + (k & 31);
  o[b] = hi;
  o[b + 32] = lo;
}
__global__ __launch_bounds__(256) void pack_bf16_kernel(const float* __restrict__ w,
                                                        u16* __restrict__ o, int n8) {
  int i = blockIdx.x * 256 + threadIdx.x;
  if (i >= n8) return;
  const float4* s = (const float4*)w + (size_t)i * 2;
  float4 a = s[0], b = s[1];
  u16 r[8] = {bf16_rne(a.x), bf16_rne(a.y), bf16_rne(a.z), bf16_rne(a.w),
              bf16_rne(b.x), bf16_rne(b.y), bf16_rne(b.z), bf16_rne(b.w)};
  *(uint4*)(o + (size_t)i * 8) = *(uint4*)r;
}

// ---------- RMSNorm. MODE 0: write dual-plane u16. MODE 1: write f32 + bf16 ----------
template <int MODE>
__global__ __launch_bounds__(256) void rmsnorm_kernel(
    const float* __restrict__ x, const float* __restrict__ scale,
    u16* __restrict__ odp, float* __restrict__ of32, u16* __restrict__ ob16) {
  const int s = blockIdx.x;
  const float* row = x + (size_t)s * kD;
  const int c = threadIdx.x * 4;
  float4 v = *(const float4*)(row + c);
  float ss = v.x * v.x + v.y * v.y + v.z * v.z + v.w * v.w;
#pragma unroll
  for (int m = 32; m; m >>= 1) ss += __shfl_xor(ss, m);
  __shared__ float wsum[4];
  if ((threadIdx.x & 63) == 0) wsum[threadIdx.x >> 6] = ss;
  __syncthreads();
  float tot = wsum[0] + wsum[1] + wsum[2] + wsum[3];
  float rinv = 1.0f / sqrtf(tot * (1.0f / kD) + 1e-5f);
  float4 sc = *(const float4*)(scale + c);
  float n[4] = {v.x * rinv * sc.x, v.y * rinv * sc.y, v.z * rinv * sc.z, v.w * rinv * sc.w};
  if (MODE == 0) {
    u16 hv[4], lv[4];
#pragma unroll
    for (int j = 0; j < 4; j++) {
      hv[j] = bf16_rne(n[j]);
      lv[j] = bf16_rne(n[j] - bf16_f32(hv[j]));
    }
    u16* o = odp + (size_t)s * 2048 + (size_t)(c >> 5) * 64 + (c & 31);
    *(uint2*)o = *(uint2*)hv;
    *(uint2*)(o + 32) = *(uint2*)lv;
  } else {
    *(float4*)(of32 + (size_t)s * kD + c) = make_float4(n[0], n[1], n[2], n[3]);
    u16* o = ob16 + (size_t)s * kD + c;
    o[0] = bf16_rne(n[0]); o[1] = bf16_rne(n[1]); o[2] = bf16_rne(n[2]); o[3] = bf16_rne(n[3]);
  }
}

// ---------- split-bf16 4-term GEMM, 2-phase prefetch, gload_lds + XOR swizzle ----------
// APK=0: A is dual-plane u16 [M][2K]; APK=1: A is packed u32 [M][K] (unpack on read).
// OUT=0: QKV epilogue -> packed u32 q/k/v [2048][1024]; OUT=1: of = resid + acc (f32, N=1024)
template <int APK, int OUT>
__global__ __launch_bounds__(256) void gemm_dp(
    const void* __restrict__ Av, const u16* __restrict__ Bdp,
    const float* __restrict__ resid, int K,
    u32* __restrict__ oq, u32* __restrict__ ok, u32* __restrict__ ov,
    float* __restrict__ of) {
  __shared__ u16 As[2][128 * 64];  // 16 KB per buf (raw bytes; u32 view when APK)
  __shared__ u16 Bs[2][128 * 64];
  const int tid = threadIdx.x, w = tid >> 6, l = tid & 63;
  const int m0 = blockIdx.y * 128, n0 = blockIdx.x * 128;
  const int wr = (w >> 1) * 64, wc = (w & 1) * 64;
  const char* Ab = (const char*)Av;
  const char* Bb = (const char*)Bdp;
  const size_t rowb = (size_t)K * 4;  // dp: 2K u16 = 4K B; pk: K u32 = 4K B

  size_t asrc[4], bsrc[4];
  int dst[4];
#pragma unroll
  for (int i = 0; i < 4; i++) {
    int fl = i * 256 + tid;
    int row = fl >> 3, cb = fl & 7;
    size_t coff = (size_t)((cb ^ (row & 7)) * 16);
    asrc[i] = (size_t)(m0 + row) * rowb + coff;
    bsrc[i] = (size_t)(n0 + row) * rowb + coff;
    dst[i] = fl * 16;
  }

  f32x4 zero = {0.f, 0.f, 0.f, 0.f};
  f32x4 acc[4][4];
#pragma unroll
  for (int i = 0; i < 4; i++)
#pragma unroll
    for (int j = 0; j < 4; j++) acc[i][j] = zero;

  auto stage = [&](int buf, int s) {
    const char* ap = Ab + (size_t)s * 128;
    const char* bp = Bb + (size_t)s * 128;
#pragma unroll
    for (int i = 0; i < 4; i++) {
      gload_lds16(ap + asrc[i], (char*)&As[buf][0] + dst[i]);
      gload_lds16(bp + bsrc[i], (char*)&Bs[buf][0] + dst[i]);
    }
  };

  const int NS = K / 32;
  stage(0, 0);
  __syncthreads();
  for (int s = 0; s < NS; s++) {
    const int cur = s & 1;
    if (s + 1 < NS) stage(cur ^ 1, s + 1);
    bf16x8 ah[4], al[4], bh[4], bl[4];
    const int g = l >> 4;
    if (APK) {
      const u32* At = (const u32*)&As[cur][0];
#pragma unroll
      for (int mi = 0; mi < 4; mi++) {
        int row = wr + mi * 16 + (l & 15);
        u32 t[8];
        *(uint4*)t = *(const uint4*)&At[row * 32 + (((2 * g) ^ (row & 7)) * 4)];
        *(uint4*)(t + 4) = *(const uint4*)&At[row * 32 + (((2 * g + 1) ^ (row & 7)) * 4)];
        unpack8(t, ah[mi], al[mi]);
      }
    } else {
#pragma unroll
      for (int mi = 0; mi < 4; mi++) {
        int row = wr + mi * 16 + (l & 15);
        ah[mi] = *(const bf16x8*)&As[cur][row * 64 + ((g ^ (row & 7)) * 8)];
        al[mi] = *(const bf16x8*)&As[cur][row * 64 + (((4 + g) ^ (row & 7)) * 8)];
      }
    }
#pragma unroll
    for (int ni = 0; ni < 4; ni++) {
      int row = wc + ni * 16 + (l & 15);
      bh[ni] = *(const bf16x8*)&Bs[cur][row * 64 + ((g ^ (row & 7)) * 8)];
      bl[ni] = *(const bf16x8*)&Bs[cur][row * 64 + (((4 + g) ^ (row & 7)) * 8)];
    }
#pragma unroll
    for (int mi = 0; mi < 4; mi++)
#pragma unroll
      for (int ni = 0; ni < 4; ni++) {
        f32x4 c = acc[mi][ni];
        c = MFMA_BF16(al[mi], bl[ni], c);
        c = MFMA_BF16(al[mi], bh[ni], c);
        c = MFMA_BF16(ah[mi], bl[ni], c);
        c = MFMA_BF16(ah[mi], bh[ni], c);
        acc[mi][ni] = c;
      }
    __syncthreads();
  }

  if (OUT == 0) {
    u32* dstp;
    int nb;
    if (n0 < 1024) { dstp = oq; nb = n0; }
    else if (n0 < 2048) { dstp = ok; nb = n0 - 1024; }
    else { dstp = ov; nb = n0 - 2048; }
#pragma unroll
    for (int mi = 0; mi < 4; mi++)
#pragma unroll
      for (int ni = 0; ni < 4; ni++)
#pragma unroll
        for (int r = 0; r < 4; r++) {
          int row = m0 + wr + mi * 16 + ((l >> 4) << 2) + r;
          int col = nb + wc + ni * 16 + (l & 15);
          dstp[(size_t)row * 1024 + col] = pack_hl(acc[mi][ni][r]);
        }
  } else {
#pragma unroll
    for (int mi = 0; mi < 4; mi++)
#pragma unroll
      for (int ni = 0; ni < 4; ni++)
#pragma unroll
        for (int r = 0; r < 4; r++) {
          int row = m0 + wr + mi * 16 + ((l >> 4) << 2) + r;
          int col = n0 + wc + ni * 16 + (l & 15);
          of[(size_t)row * 1024 + col] = resid[(size_t)row * 1024 + col] + acc[mi][ni][r];
        }
  }
}

// ---------- flash attention (unchanged from validated round-2 version) ----------
__global__ __launch_bounds__(256) void attn_kernel(
    const u32* __restrict__ Qp, const u32* __restrict__ Kp, const u32* __restrict__ Vp,
    u32* __restrict__ Op) {
  constexpr int LDK = 68;
  __shared__ u32 Ks[64 * LDK];
  __shared__ u32 Vs[64 * LDK];
  __shared__ u32 Ps[64 * LDK];
  const int tid = threadIdx.x, w = tid >> 6, l = tid & 63;
  const int qt = blockIdx.x, hh = blockIdx.y;
  const int q0 = qt * 64, hc = hh * 64;

  bf16x8 qh[2], ql[2];
  {
    const int qrow = q0 + w * 16 + (l & 15);
#pragma unroll
    for (int kk = 0; kk < 2; kk++) {
      u32 t[8];
      const u32* p = Qp + (size_t)qrow * kD + hc + kk * 32 + ((l >> 4) << 3);
      *(uint4*)t = *(const uint4*)p;
      *(uint4*)(t + 4) = *(const uint4*)(p + 4);
      unpack8(t, qh[kk], ql[kk]);
    }
  }
  float mrun[4], lrun[4];
  f32x4 zero = {0.f, 0.f, 0.f, 0.f};
  f32x4 oacc[4];
#pragma unroll
  for (int r = 0; r < 4; r++) { mrun[r] = -3.0e38f; lrun[r] = 0.f; }
#pragma unroll
  for (int vb = 0; vb < 4; vb++) oacc[vb] = zero;

  for (int kt = 0; kt <= qt; kt++) {
    __syncthreads();
    {
      const int trow = tid >> 2, c0 = (tid & 3) * 16;
      const u32* gK = Kp + (size_t)(kt * 64 + trow) * kD + hc + c0;
      u32* sK = Ks + trow * LDK + c0;
      *(uint4*)sK = *(const uint4*)gK;
      *(uint4*)(sK + 4) = *(const uint4*)(gK + 4);
      *(uint4*)(sK + 8) = *(const uint4*)(gK + 8);
      *(uint4*)(sK + 12) = *(const uint4*)(gK + 12);
      const u32* gV = Vp + (size_t)(kt * 64 + trow) * kD + hc + c0;
#pragma unroll
      for (int j = 0; j < 16; j += 4) {
        uint4 v = *(const uint4*)(gV + j);
        Vs[(c0 + j + 0) * LDK + trow] = v.x;
        Vs[(c0 + j + 1) * LDK + trow] = v.y;
        Vs[(c0 + j + 2) * LDK + trow] = v.z;
        Vs[(c0 + j + 3) * LDK + trow] = v.w;
      }
    }
    __syncthreads();

    f32x4 sfr[4];
#pragma unroll
    for (int kb = 0; kb < 4; kb++) {
      f32x4 sa = zero;
#pragma unroll
      for (int kk = 0; kk < 2; kk++) {
        u32 t[8];
        bf16x8 kh, kl;
        const u32* p = Ks + (kb * 16 + (l & 15)) * LDK + kk * 32 + ((l >> 4) << 3);
        *(uint4*)t = *(const uint4*)p;
        *(uint4*)(t + 4) = *(const uint4*)(p + 4);
        unpack8(t, kh, kl);
        sa = MFMA_BF16(ql[kk], kl, sa);
        sa = MFMA_BF16(ql[kk], kh, sa);
        sa = MFMA_BF16(qh[kk], kl, sa);
        sa = MFMA_BF16(qh[kk], kh, sa);
      }
      sfr[kb] = sa * 0.125f;
    }
    if (kt == qt) {
#pragma unroll
      for (int kb = 0; kb < 4; kb++) {
        int t = kt * 64 + kb * 16 + (l & 15);
#pragma unroll
        for (int r = 0; r < 4; r++) {
          int qq = q0 + w * 16 + ((l >> 4) << 2) + r;
          if (t > qq) sfr[kb][r] = -3.0e38f;
        }
      }
    }
#pragma unroll
    for (int r = 0; r < 4; r++) {
      float mx = fmaxf(fmaxf(sfr[0][r], sfr[1][r]), fmaxf(sfr[2][r], sfr[3][r]));
#pragma unroll
      for (int mm = 1; mm < 16; mm <<= 1) mx = fmaxf(mx, __shfl_xor(mx, mm));
      float mnew = fmaxf(mrun[r], mx);
      float sf = __expf(mrun[r] - mnew);
      mrun[r] = mnew;
      float rs = 0.f;
#pragma unroll
      for (int kb = 0; kb < 4; kb++) {
        float p = __expf(sfr[kb][r] - mnew);
        sfr[kb][r] = p;
        rs += p;
      }
#pragma unroll
      for (int mm = 1; mm < 16; mm <<= 1) rs += __shfl_xor(rs, mm);
      lrun[r] = lrun[r] * sf + rs;
#pragma unroll
      for (int vb = 0; vb < 4; vb++) oacc[vb][r] *= sf;
    }
#pragma unroll
    for (int kb = 0; kb < 4; kb++)
#pragma unroll
      for (int r = 0; r < 4; r++)
        Ps[(w * 16 + ((l >> 4) << 2) + r) * LDK + kb * 16 + (l & 15)] = pack_hl(sfr[kb][r]);
#pragma unroll
    for (int ks = 0; ks < 2; ks++) {
      bf16x8 ph, pl;
      {
        u32 t[8];
        const u32* pp = Ps + (w * 16 + (l & 15)) * LDK + ks * 32 + ((l >> 4) << 3);
        *(uint4*)t = *(const uint4*)pp;
        *(uint4*)(t + 4) = *(const uint4*)(pp + 4);
        unpack8(t, ph, pl);
      }
#pragma unroll
      for (int vb = 0; vb < 4; vb++) {
        u32 t2[8];
        bf16x8 vh, vl;
        const u32* pv = Vs + (vb * 16 + (l & 15)) * LDK + ks * 32 + ((l >> 4) << 3);
        *(uint4*)t2 = *(const uint4*)pv;
        *(uint4*)(t2 + 4) = *(const uint4*)(pv + 4);
        unpack8(t2, vh, vl);
        f32x4 c = oacc[vb];
        c = MFMA_BF16(pl, vl, c);
        c = MFMA_BF16(pl, vh, c);
        c = MFMA_BF16(ph, vl, c);
        c = MFMA_BF16(ph, vh, c);
        oacc[vb] = c;
      }
    }
  }
#pragma unroll
  for (int vb = 0; vb < 4; vb++)
#pragma unroll
    for (int r = 0; r < 4; r++) {
      float o = oacc[vb][r] / lrun[r];
      int row = q0 + w * 16 + ((l >> 4) << 2) + r;
      int col = hc + vb * 16 + (l & 15);
      Op[(size_t)row * kD + col] = pack_hl(o);
    }
}

// ---------- router ----------
__global__ __launch_bounds__(256) void router_kernel(
    const float* __restrict__ normed, const float* __restrict__ Wg,
    float* __restrict__ probs, float* __restrict__ gates,
    int* __restrict__ experts, int* __restrict__ counts) {
  const int w = threadIdx.x >> 6, l = threadIdx.x & 63;
  const int s = blockIdx.x * 4 + w;
  float lg[kE];
  const float* row = normed + (size_t)s * kD;
#pragma unroll
  for (int e = 0; e < kE; e++) {
    const float* wg = Wg + (size_t)e * kD;
    float a = 0.f;
    for (int d = l; d < kD; d += 64) a += row[d] * wg[d];
#pragma unroll
    for (int m = 32; m; m >>= 1) a += __shfl_xor(a, m);
    lg[e] = a;
  }
  if (l == 0) {
    float mx = lg[0];
#pragma unroll
    for (int e = 1; e < kE; e++) mx = fmaxf(mx, lg[e]);
    float p[kE], sum = 0.f;
#pragma unroll
    for (int e = 0; e < kE; e++) { p[e] = __expf(lg[e] - mx); sum += p[e]; }
    float inv = 1.f / sum;
#pragma unroll
    for (int e = 0; e < kE; e++) { p[e] *= inv; probs[(size_t)s * kE + e] = p[e]; }
    int i1 = 0;
#pragma unroll
    for (int e = 1; e < kE; e++) if (lg[e] > lg[i1]) i1 = e;
    int i2 = (i1 == 0) ? 1 : 0;
#pragma unroll
    for (int e = 0; e < kE; e++) if (e != i1 && lg[e] > lg[i2]) i2 = e;
    float den = 1.f / (p[i1] + p[i2]);
    gates[s * 2] = p[i1] * den;
    gates[s * 2 + 1] = p[i2] * den;
    experts[s * 2] = i1;
    experts[s * 2 + 1] = i2;
    atomicAdd(&counts[i1], 1);
    atomicAdd(&counts[i2], 1);
  }
}

__global__ void moe_init(int* counts) {
  if (threadIdx.x < kE) counts[threadIdx.x] = 0;
}
__global__ void moe_scan(const int* __restrict__ counts, int* __restrict__ ebase,
                         int* __restrict__ cursor) {
  if (threadIdx.x == 0) {
    int acc = 0;
    for (int e = 0; e < kE; e++) { ebase[e] = acc; cursor[e] = acc; acc += counts[e]; }
    ebase[kE] = acc;
  }
}
__global__ void moe_fill(const int* __restrict__ experts, int* __restrict__ cursor,
                         int* __restrict__ slot_list, int* __restrict__ slot_of) {
  int s = blockIdx.x * 256 + threadIdx.x;
  if (s >= kS) return;
  for (int k = 0; k < 2; k++) {
    int e = experts[s * 2 + k];
    int pos = atomicAdd(&cursor[e], 1);
    slot_list[pos] = s;
    slot_of[s * 2 + k] = pos;
  }
}

// ---------- MoE fused GEMM: U[slot][n] = bf16(gelu(A·W_in) * (A·W_v)) ----------
// 256x128 tile, BK=64, 512 threads, 2-phase prefetch, 128 KiB LDS
__global__ __launch_bounds__(512) void moe_mm1(
    const u16* __restrict__ A, const u16* __restrict__ B1g, const u16* __restrict__ B2g,
    const int* __restrict__ slot_list, const int* __restrict__ ebase,
    u16* __restrict__ Uo) {
  const int e = blockIdx.z;
  const int base = ebase[e];
  const int Me = ebase[e + 1] - base;
  const int m0 = blockIdx.y * 256;
  if (m0 >= Me) return;
  const int n0 = blockIdx.x * 128;
  __shared__ u16 As[2][256 * 64];
  __shared__ u16 B1s[2][128 * 64];
  __shared__ u16 B2s[2][128 * 64];
  const int tid = threadIdx.x, w = tid >> 6, l = tid & 63;
  const int wr = (w >> 2) * 128, wc = (w & 3) * 32;
  const char* B1 = (const char*)(B1g + (size_t)e * kFF * kD);
  const char* B2 = (const char*)(B2g + (size_t)e * kFF * kD);

  size_t asrc[4], bsrc[2];
  int adst[4], bdst[2];
#pragma unroll
  for (int i = 0; i < 4; i++) {
    int fl = i * 512 + tid;
    int row = fl >> 3, cb = fl & 7;
    int mr = m0 + row;
    if (mr > Me - 1) mr = Me - 1;
    int ar = slot_list[base + mr];
    asrc[i] = (size_t)ar * 2048 + (size_t)((cb ^ (row & 7)) * 16);
    adst[i] = fl * 16;
  }
#pragma unroll
  for (int i = 0; i < 2; i++) {
    int fl = i * 512 + tid;
    int row = fl >> 3, cb = fl & 7;
    bsrc[i] = (size_t)(n0 + row) * 2048 + (size_t)((cb ^ (row & 7)) * 16);
    bdst[i] = fl * 16;
  }

  f32x4 zero = {0.f, 0.f, 0.f, 0.f};
  f32x4 acc1[8][2], acc2[8][2];
#pragma unroll
  for (int i = 0; i < 8; i++)
#pragma unroll
    for (int j = 0; j < 2; j++) { acc1[i][j] = zero; acc2[i][j] = zero; }

  auto stage = [&](int buf, int s) {
    const size_t so = (size_t)s * 128;
    const char* ab = (const char*)A + so;
#pragma unroll
    for (int i = 0; i < 4; i++) gload_lds16(ab + asrc[i], (char*)&As[buf][0] + adst[i]);
#pragma unroll
    for (int i = 0; i < 2; i++) {
      gload_lds16(B1 + so + bsrc[i], (char*)&B1s[buf][0] + bdst[i]);
      gload_lds16(B2 + so + bsrc[i], (char*)&B2s[buf][0] + bdst[i]);
    }
  };

  const int NS = kD / 64;  // 16
  stage(0, 0);
  __syncthreads();
  for (int s = 0; s < NS; s++) {
    const int cur = s & 1;
    if (s + 1 < NS) stage(cur ^ 1, s + 1);
#pragma unroll
    for (int kk = 0; kk < 2; kk++) {
      const int g = kk * 4 + (l >> 4);
      bf16x8 af[8], b1f[2], b2f[2];
#pragma unroll
      for (int mi = 0; mi < 8; mi++) {
        int row = wr + mi * 16 + (l & 15);
        af[mi] = *(const bf16x8*)&As[cur][row * 64 + ((g ^ (row & 7)) * 8)];
      }
#pragma unroll
      for (int ni = 0; ni < 2; ni++) {
        int row = wc + ni * 16 + (l & 15);
        int bo = row * 64 + ((g ^ (row & 7)) * 8);
        b1f[ni] = *(const bf16x8*)&B1s[cur][bo];
        b2f[ni] = *(const bf16x8*)&B2s[cur][bo];
      }
#pragma unroll
      for (int mi = 0; mi < 8; mi++)
#pragma unroll
        for (int ni = 0; ni < 2; ni++) {
          acc1[mi][ni] = MFMA_BF16(af[mi], b1f[ni], acc1[mi][ni]);
          acc2[mi][ni] = MFMA_BF16(af[mi], b2f[ni], acc2[mi][ni]);
        }
    }
    __syncthreads();
  }

#pragma unroll
  for (int mi = 0; mi < 8; mi++)
#pragma unroll
    for (int r = 0; r < 4; r++) {
      int ml = m0 + wr + mi * 16 + ((l >> 4) << 2) + r;
      if (ml >= Me) continue;
      size_t rb = (size_t)(base + ml) * kFF;
#pragma unroll
      for (int ni = 0; ni < 2; ni++) {
        int col = n0 + wc + ni * 16 + (l & 15);
        float u = acc1[mi][ni][r], v2 = acc2[mi][ni][r];
        float ge = 0.5f * u * (1.0f + erff(u * 0.70710678118654752f));
        Uo[rb + col] = bf16_rne(ge * v2);
      }
    }
}

// ---------- MoE out GEMM: eo[slot][n] = U[slot] · W_out[e][n], 128x128, BK=64, 2-phase ----------
__global__ __launch_bounds__(256) void moe_mm2(
    const u16* __restrict__ U, const u16* __restrict__ Bg,
    const int* __restrict__ ebase, float* __restrict__ eo) {
  const int e = blockIdx.z;
  const int base = ebase[e];
  const int Me = ebase[e + 1] - base;
  const int m0 = blockIdx.y * 128;
  if (m0 >= Me) return;
  const int n0 = blockIdx.x * 128;
  __shared__ u16 As[2][128 * 64];
  __shared__ u16 Bs[2][128 * 64];
  const int tid = threadIdx.x, w = tid >> 6, l = tid & 63;
  const int wr = (w >> 1) * 64, wc = (w & 1) * 64;
  const char* B = (const char*)(Bg + (size_t)e * kD * kFF);

  size_t asrc[4], bsrc[4];
  int dst[4];
#pragma unroll
  for (int i = 0; i < 4; i++) {
    int fl = i * 256 + tid;
    int row = fl >> 3, cb = fl & 7;
    size_t coff = (size_t)((cb ^ (row & 7)) * 16);
    int mr = m0 + row;
    if (mr > Me - 1) mr = Me - 1;
    asrc[i] = (size_t)(base + mr) * 8192 + coff;
    bsrc[i] = (size_t)(n0 + row) * 8192 + coff;
    dst[i] = fl * 16;
  }

  f32x4 zero = {0.f, 0.f, 0.f, 0.f};
  f32x4 acc[4][4];
#pragma unroll
  for (int i = 0; i < 4; i++)
#pragma unroll
    for (int j = 0; j < 4; j++) acc[i][j] = zero;

  auto stage = [&](int buf, int s) {
    const size_t so = (size_t)s * 128;
#pragma unroll
    for (int i = 0; i < 4; i++) {
      gload_lds16((const char*)U + so + asrc[i], (char*)&As[buf][0] + dst[i]);
      gload_lds16(B + so + bsrc[i], (char*)&Bs[buf][0] + dst[i]);
    }
  };

  const int NS = kFF / 64;  // 64
  stage(0, 0);
  __syncthreads();
  for (int s = 0; s < NS; s++) {
    const int cur = s & 1;
    if (s + 1 < NS) stage(cur ^ 1, s + 1);
#pragma unroll
    for (int kk = 0; kk < 2; kk++) {
      const int g = kk * 4 + (l >> 4);
      bf16x8 af[4], bf[4];
#pragma unroll
      for (int mi = 0; mi < 4; mi++) {
        int row = wr + mi * 16 + (l & 15);
        af[mi] = *(const bf16x8*)&As[cur][row * 64 + ((g ^ (row & 7)) * 8)];
      }
#pragma unroll
      for (int ni = 0; ni < 4; ni++) {
        int row = wc + ni * 16 + (l & 15);
        bf[ni] = *(const bf16x8*)&Bs[cur][row * 64 + ((g ^ (row & 7)) * 8)];
      }
#pragma unroll
      for (int mi = 0; mi < 4; mi++)
#pragma unroll
        for (int ni = 0; ni < 4; ni++) acc[mi][ni] = MFMA_BF16(af[mi], bf[ni], acc[mi][ni]);
    }
    __syncthreads();
  }

#pragma unroll
  for (int mi = 0; mi < 4; mi++)
#pragma unroll
    for (int r = 0; r < 4; r++) {
      int ml = m0 + wr + mi * 16 + ((l >> 4) << 2) + r;
      if (ml >= Me) continue;
      size_t rb = (size_t)(base + ml) * kD;
#pragma unroll
      for (int ni = 0; ni < 4; ni++) {
        int col = n0 + wc + ni * 16 + (l & 15);
        eo[rb + col] = acc[mi][ni][r];
      }
    }
}

// ---------- final combine ----------
__global__ __launch_bounds__(256) void combine_kernel(
    const float* __restrict__ h, const float* __restrict__ eo,
    const float* __restrict__ gates, const int* __restrict__ slot_of,
    float* __restrict__ out) {
  const int s = blockIdx.x;
  const float g0 = gates[s * 2], g1 = gates[s * 2 + 1];
  const int p0 = slot_of[s * 2], p1 = slot_of[s * 2 + 1];
  const int c = threadIdx.x * 4;
  float4 hv = *(const float4*)(h + (size_t)s * kD + c);
  float4 e0 = *(const float4*)(eo + (size_t)p0 * kD + c);
  float4 e1 = *(const float4*)(eo + (size_t)p1 * kD + c);
  float4 o;
  o.x = hv.x + g0 * e0.x + g1 * e1.x;
  o.y = hv.y + g0 * e0.y + g1 * e1.y;
  o.z = hv.z + g0 * e0.z + g1 * e1.z;
  o.w = hv.w + g0 * e0.w + g1 * e1.w;
  *(float4*)(out + (size_t)s * kD + c) = o;
}

extern "C" void kernel_launch(void* const* d_in, const int* in_sizes, int n_in,
                              void* d_out, int out_size, void* d_ws, size_t ws_size,
                              hipStream_t stream) {
  (void)in_sizes; (void)n_in; (void)out_size; (void)ws_size;
  const float* x = (const float*)d_in[0];
  const float* scale_attn = (const float*)d_in[2];
  const float* Wq = (const float*)d_in[3];
  const float* Wk = (const float*)d_in[4];
  const float* Wv = (const float*)d_in[5];
  const float* Wo = (const float*)d_in[6];
  const float* scale_ffn = (const float*)d_in[7];
  const float* Wg = (const float*)d_in[8];
  const float* W_in = (const float*)d_in[9];
  const float* W_vv = (const float*)d_in[10];
  const float* W_out = (const float*)d_in[11];
  float* out = (float*)d_out;
  float* probs = out + (size_t)kS * kD;

  char* wsb = (char*)d_ws;
  size_t off = 0;
  auto alloc = [&](size_t bytes) -> void* {
    void* p = wsb + off;
    off += (bytes + 255) & ~(size_t)255;
    return p;
  };
  const size_t SDu = (size_t)kS * kD;
  const size_t EW = (size_t)kE * kFF * kD;
  u16* normA_dp = (u16*)alloc(SDu * 2 * 2);
  u32* qpk = (u32*)alloc(SDu * 4);
  u32* kpk = (u32*)alloc(SDu * 4);
  u32* vpk = (u32*)alloc(SDu * 4);
  u32* ctxpk = (u32*)alloc(SDu * 4);
  float* h = (float*)alloc(SDu * 4);
  float* normFf = (float*)alloc(SDu * 4);
  u16* normFb = (u16*)alloc(SDu * 2);
  u16* Wqkv_dp = (u16*)alloc((size_t)3072 * 2048 * 2);
  u16* Wo_dp = (u16*)alloc((size_t)1024 * 2048 * 2);
  u16* Win_bf = (u16*)alloc(EW * 2);
  u16* Wv_bf = (u16*)alloc(EW * 2);
  u16* Wout_bf = (u16*)alloc(EW * 2);
  u16* U = (u16*)alloc((size_t)kSlots * kFF * 2);
  float* eo = (float*)alloc((size_t)kSlots * kD * 4);
  float* gates = (float*)alloc(kS * 2 * 4);
  int* experts = (int*)alloc(kS * 2 * 4);
  int* slot_of = (int*)alloc(kS * 2 * 4);
  int* slot_list = (int*)alloc(kSlots * 4);
  int* counts = (int*)alloc(64);
  int* ebase = (int*)alloc(64);
  int* cursor = (int*)alloc(64);

  pack_dp3<<<(3072 * 1024) / 256, 256, 0, stream>>>(Wq, Wk, Wv, Wqkv_dp);
  pack_dp1<<<(1024 * 1024) / 256, 256, 0, stream>>>(Wo, Wo_dp, 1024 * 1024);
  const int n8 = (int)(EW / 8);
  pack_bf16_kernel<<<(n8 + 255) / 256, 256, 0, stream>>>(W_in, Win_bf, n8);
  pack_bf16_kernel<<<(n8 + 255) / 256, 256, 0, stream>>>(W_vv, Wv_bf, n8);
  pack_bf16_kernel<<<(n8 + 255) / 256, 256, 0, stream>>>(W_out, Wout_bf, n8);

  rmsnorm_kernel<0><<<kS, 256, 0, stream>>>(x, scale_attn, normA_dp, nullptr, nullptr);
  gemm_dp<0, 0><<<dim3(3072 / 128, kS / 128), 256, 0, stream>>>(
      normA_dp, Wqkv_dp, nullptr, kD, qpk, kpk, vpk, nullptr);
  attn_kernel<<<dim3(kS / 64, kH), 256, 0, stream>>>(qpk, kpk, vpk, ctxpk);
  gemm_dp<1, 1><<<dim3(1024 / 128, kS / 128), 256, 0, stream>>>(
      ctxpk, Wo_dp, x, kD, nullptr, nullptr, nullptr, h);

  rmsnorm_kernel<1><<<kS, 256, 0, stream>>>(h, scale_ffn, nullptr, normFf, normFb);
  moe_init<<<1, 64, 0, stream>>>(counts);
  router_kernel<<<kS / 4, 256, 0, stream>>>(normFf, Wg, probs, gates, experts, counts);
  moe_scan<<<1, 64, 0, stream>>>(counts, ebase, cursor);
  moe_fill<<<kS / 256, 256, 0, stream>>>(experts, cursor, slot_list, slot_of);

  moe_mm1<<<dim3(kFF / 128, kSlots / 256, kE), 512, 0, stream>>>(
      normFb, Win_bf, Wv_bf, slot_list, ebase, U);
  moe_mm2<<<dim3(kD / 128, kSlots / 128, kE), 256, 0, stream>>>(
      U, Wout_bf, ebase, eo);

  combine_kernel<<<kS, 256, 0, stream>>>(h, eo, gates, slot_of, out);
}

// Round 4
// 699.212 us; speedup vs baseline: 1.4225x; 1.0192x over previous
//
#include <hip/hip_runtime.h>
#include <hip/hip_bf16.h>
#include <math.h>

typedef unsigned int u32;
typedef unsigned short u16;
using bf16x8 = __attribute__((ext_vector_type(8))) short;
using f32x4 = __attribute__((ext_vector_type(4))) float;

#define MFMA_BF16(a, b, c) __builtin_amdgcn_mfma_f32_16x16x32_bf16((a), (b), (c), 0, 0, 0)
#define VMCNT8() asm volatile("s_waitcnt vmcnt(8)" ::: "memory")
#define VMCNT0() asm volatile("s_waitcnt vmcnt(0)" ::: "memory")
#define SBAR() __builtin_amdgcn_s_barrier()
#define SCHED0() __builtin_amdgcn_sched_barrier(0)

constexpr int kS = 2048, kD = 1024, kH = 16, kE = 8, kFF = 4096;
constexpr int kSlots = kS * 2;

// ---------- numeric helpers ----------
__device__ __forceinline__ u16 bf16_rne(float f) {
  u32 u = __float_as_uint(f);
  u32 r = (u + 0x7fffu + ((u >> 16) & 1u)) >> 16;
  return (u16)r;
}
__device__ __forceinline__ float bf16_f32(u16 h) { return __uint_as_float(((u32)h) << 16); }
__device__ __forceinline__ u32 pack_hl(float x) {
  u16 hi = bf16_rne(x);
  u16 lo = bf16_rne(x - bf16_f32(hi));
  return ((u32)lo << 16) | (u32)hi;
}
__device__ __forceinline__ void unpack8(const u32* t, bf16x8& h, bf16x8& l) {
#pragma unroll
  for (int j = 0; j < 8; j++) {
    h[j] = (short)(t[j] & 0xffffu);
    l[j] = (short)(t[j] >> 16);
  }
}
__device__ __forceinline__ void gload_lds16(const void* g, void* l) {
  __builtin_amdgcn_global_load_lds((const __attribute__((address_space(1))) u32*)g,
                                   (__attribute__((address_space(3))) u32*)l, 16, 0, 0);
}

// ---------- weight packs ----------
__global__ __launch_bounds__(256) void pack_dp3(const float* __restrict__ Wq,
                                                const float* __restrict__ Wk,
                                                const float* __restrict__ Wv,
                                                u16* __restrict__ o) {
  int i = blockIdx.x * 256 + threadIdx.x;
  if (i >= 3072 * 1024) return;
  int n = i >> 10, k = i & 1023;
  float v = (n < 1024) ? Wq[i] : (n < 2048) ? Wk[i - 1024 * 1024] : Wv[i - 2048 * 1024];
  u16 hi = bf16_rne(v);
  u16 lo = bf16_rne(v - bf16_f32(hi));
  size_t b = (size_t)n * 2048 + (size_t)(k >> 5) * 64 + (k & 31);
  o[b] = hi;
  o[b + 32] = lo;
}
__global__ __launch_bounds__(256) void pack_dp1(const float* __restrict__ W,
                                                u16* __restrict__ o, int n_elem) {
  int i = blockIdx.x * 256 + threadIdx.x;
  if (i >= n_elem) return;
  int k = i & 1023, n = i >> 10;
  float v = W[i];
  u16 hi = bf16_rne(v);
  u16 lo = bf16_rne(v - bf16_f32(hi));
  size_t b = (size_t)n * 2048 + (size_t)(k >> 5) * 64 + (k & 31);
  o[b] = hi;
  o[b + 32] = lo;
}
__global__ __launch_bounds__(256) void pack_bf16_kernel(const float* __restrict__ w,
                                                        u16* __restrict__ o, int n8) {
  int i = blockIdx.x * 256 + threadIdx.x;
  if (i >= n8) return;
  const float4* s = (const float4*)w + (size_t)i * 2;
  float4 a = s[0], b = s[1];
  u16 r[8] = {bf16_rne(a.x), bf16_rne(a.y), bf16_rne(a.z), bf16_rne(a.w),
              bf16_rne(b.x), bf16_rne(b.y), bf16_rne(b.z), bf16_rne(b.w)};
  *(uint4*)(o + (size_t)i * 8) = *(uint4*)r;
}

// ---------- RMSNorm. MODE 0: write dual-plane u16. MODE 1: write f32 + bf16 ----------
template <int MODE>
__global__ __launch_bounds__(256) void rmsnorm_kernel(
    const float* __restrict__ x, const float* __restrict__ scale,
    u16* __restrict__ odp, float* __restrict__ of32, u16* __restrict__ ob16) {
  const int s = blockIdx.x;
  const float* row = x + (size_t)s * kD;
  const int c = threadIdx.x * 4;
  float4 v = *(const float4*)(row + c);
  float ss = v.x * v.x + v.y * v.y + v.z * v.z + v.w * v.w;
#pragma unroll
  for (int m = 32; m; m >>= 1) ss += __shfl_xor(ss, m);
  __shared__ float wsum[4];
  if ((threadIdx.x & 63) == 0) wsum[threadIdx.x >> 6] = ss;
  __syncthreads();
  float tot = wsum[0] + wsum[1] + wsum[2] + wsum[3];
  float rinv = 1.0f / sqrtf(tot * (1.0f / kD) + 1e-5f);
  float4 sc = *(const float4*)(scale + c);
  float n[4] = {v.x * rinv * sc.x, v.y * rinv * sc.y, v.z * rinv * sc.z, v.w * rinv * sc.w};
  if (MODE == 0) {
    u16 hv[4], lv[4];
#pragma unroll
    for (int j = 0; j < 4; j++) {
      hv[j] = bf16_rne(n[j]);
      lv[j] = bf16_rne(n[j] - bf16_f32(hv[j]));
    }
    u16* o = odp + (size_t)s * 2048 + (size_t)(c >> 5) * 64 + (c & 31);
    *(uint2*)o = *(uint2*)hv;
    *(uint2*)(o + 32) = *(uint2*)lv;
  } else {
    *(float4*)(of32 + (size_t)s * kD + c) = make_float4(n[0], n[1], n[2], n[3]);
    u16* o = ob16 + (size_t)s * kD + c;
    o[0] = bf16_rne(n[0]); o[1] = bf16_rne(n[1]); o[2] = bf16_rne(n[2]); o[3] = bf16_rne(n[3]);
  }
}

// ---------- split-bf16 4-term GEMM, counted-vmcnt 2-phase, gload_lds + XOR swizzle ----------
template <int APK, int OUT>
__global__ __launch_bounds__(256) void gemm_dp(
    const void* __restrict__ Av, const u16* __restrict__ Bdp,
    const float* __restrict__ resid, int K,
    u32* __restrict__ oq, u32* __restrict__ ok, u32* __restrict__ ov,
    float* __restrict__ of) {
  __shared__ u16 As[2][128 * 64];
  __shared__ u16 Bs[2][128 * 64];
  const int tid = threadIdx.x, w = tid >> 6, l = tid & 63;
  const int m0 = blockIdx.y * 128, n0 = blockIdx.x * 128;
  const int wr = (w >> 1) * 64, wc = (w & 1) * 64;
  const char* Ab = (const char*)Av;
  const char* Bb = (const char*)Bdp;
  const size_t rowb = (size_t)K * 4;

  size_t asrc[4], bsrc[4];
  int dst[4];
#pragma unroll
  for (int i = 0; i < 4; i++) {
    int fl = i * 256 + tid;
    int row = fl >> 3, cb = fl & 7;
    size_t coff = (size_t)((cb ^ (row & 7)) * 16);
    asrc[i] = (size_t)(m0 + row) * rowb + coff;
    bsrc[i] = (size_t)(n0 + row) * rowb + coff;
    dst[i] = fl * 16;
  }

  f32x4 zero = {0.f, 0.f, 0.f, 0.f};
  f32x4 acc[4][4];
#pragma unroll
  for (int i = 0; i < 4; i++)
#pragma unroll
    for (int j = 0; j < 4; j++) acc[i][j] = zero;

  auto stage = [&](int buf, int s) {
    const char* ap = Ab + (size_t)s * 128;
    const char* bp = Bb + (size_t)s * 128;
#pragma unroll
    for (int i = 0; i < 4; i++) {
      gload_lds16(ap + asrc[i], (char*)&As[buf][0] + dst[i]);
      gload_lds16(bp + bsrc[i], (char*)&Bs[buf][0] + dst[i]);
    }
  };

  const int NS = K / 32;
  stage(0, 0);
  for (int s = 0; s < NS; s++) {
    const int cur = s & 1;
    const bool lastit = (s == NS - 1);
    if (!lastit) stage(cur ^ 1, s + 1);
    if (!lastit) VMCNT8(); else VMCNT0();
    SBAR();
    SCHED0();
    bf16x8 ah[4], al[4], bh[4], bl[4];
    const int g = l >> 4;
    if (APK) {
      const u32* At = (const u32*)&As[cur][0];
#pragma unroll
      for (int mi = 0; mi < 4; mi++) {
        int row = wr + mi * 16 + (l & 15);
        u32 t[8];
        *(uint4*)t = *(const uint4*)&At[row * 32 + (((2 * g) ^ (row & 7)) * 4)];
        *(uint4*)(t + 4) = *(const uint4*)&At[row * 32 + (((2 * g + 1) ^ (row & 7)) * 4)];
        unpack8(t, ah[mi], al[mi]);
      }
    } else {
#pragma unroll
      for (int mi = 0; mi < 4; mi++) {
        int row = wr + mi * 16 + (l & 15);
        ah[mi] = *(const bf16x8*)&As[cur][row * 64 + ((g ^ (row & 7)) * 8)];
        al[mi] = *(const bf16x8*)&As[cur][row * 64 + (((4 + g) ^ (row & 7)) * 8)];
      }
    }
#pragma unroll
    for (int ni = 0; ni < 4; ni++) {
      int row = wc + ni * 16 + (l & 15);
      bh[ni] = *(const bf16x8*)&Bs[cur][row * 64 + ((g ^ (row & 7)) * 8)];
      bl[ni] = *(const bf16x8*)&Bs[cur][row * 64 + (((4 + g) ^ (row & 7)) * 8)];
    }
#pragma unroll
    for (int mi = 0; mi < 4; mi++)
#pragma unroll
      for (int ni = 0; ni < 4; ni++) {
        f32x4 c = acc[mi][ni];
        c = MFMA_BF16(al[mi], bl[ni], c);
        c = MFMA_BF16(al[mi], bh[ni], c);
        c = MFMA_BF16(ah[mi], bl[ni], c);
        c = MFMA_BF16(ah[mi], bh[ni], c);
        acc[mi][ni] = c;
      }
    SCHED0();
    if (!lastit) SBAR();
  }

  if (OUT == 0) {
    u32* dstp;
    int nb;
    if (n0 < 1024) { dstp = oq; nb = n0; }
    else if (n0 < 2048) { dstp = ok; nb = n0 - 1024; }
    else { dstp = ov; nb = n0 - 2048; }
#pragma unroll
    for (int mi = 0; mi < 4; mi++)
#pragma unroll
      for (int ni = 0; ni < 4; ni++)
#pragma unroll
        for (int r = 0; r < 4; r++) {
          int row = m0 + wr + mi * 16 + ((l >> 4) << 2) + r;
          int col = nb + wc + ni * 16 + (l & 15);
          dstp[(size_t)row * 1024 + col] = pack_hl(acc[mi][ni][r]);
        }
  } else {
#pragma unroll
    for (int mi = 0; mi < 4; mi++)
#pragma unroll
      for (int ni = 0; ni < 4; ni++)
#pragma unroll
        for (int r = 0; r < 4; r++) {
          int row = m0 + wr + mi * 16 + ((l >> 4) << 2) + r;
          int col = n0 + wc + ni * 16 + (l & 15);
          of[(size_t)row * 1024 + col] = resid[(size_t)row * 1024 + col] + acc[mi][ni][r];
        }
  }
}

// ---------- flash attention (unchanged, validated) ----------
__global__ __launch_bounds__(256) void attn_kernel(
    const u32* __restrict__ Qp, const u32* __restrict__ Kp, const u32* __restrict__ Vp,
    u32* __restrict__ Op) {
  constexpr int LDK = 68;
  __shared__ u32 Ks[64 * LDK];
  __shared__ u32 Vs[64 * LDK];
  __shared__ u32 Ps[64 * LDK];
  const int tid = threadIdx.x, w = tid >> 6, l = tid & 63;
  const int qt = blockIdx.x, hh = blockIdx.y;
  const int q0 = qt * 64, hc = hh * 64;

  bf16x8 qh[2], ql[2];
  {
    const int qrow = q0 + w * 16 + (l & 15);
#pragma unroll
    for (int kk = 0; kk < 2; kk++) {
      u32 t[8];
      const u32* p = Qp + (size_t)qrow * kD + hc + kk * 32 + ((l >> 4) << 3);
      *(uint4*)t = *(const uint4*)p;
      *(uint4*)(t + 4) = *(const uint4*)(p + 4);
      unpack8(t, qh[kk], ql[kk]);
    }
  }
  float mrun[4], lrun[4];
  f32x4 zero = {0.f, 0.f, 0.f, 0.f};
  f32x4 oacc[4];
#pragma unroll
  for (int r = 0; r < 4; r++) { mrun[r] = -3.0e38f; lrun[r] = 0.f; }
#pragma unroll
  for (int vb = 0; vb < 4; vb++) oacc[vb] = zero;

  for (int kt = 0; kt <= qt; kt++) {
    __syncthreads();
    {
      const int trow = tid >> 2, c0 = (tid & 3) * 16;
      const u32* gK = Kp + (size_t)(kt * 64 + trow) * kD + hc + c0;
      u32* sK = Ks + trow * LDK + c0;
      *(uint4*)sK = *(const uint4*)gK;
      *(uint4*)(sK + 4) = *(const uint4*)(gK + 4);
      *(uint4*)(sK + 8) = *(const uint4*)(gK + 8);
      *(uint4*)(sK + 12) = *(const uint4*)(gK + 12);
      const u32* gV = Vp + (size_t)(kt * 64 + trow) * kD + hc + c0;
#pragma unroll
      for (int j = 0; j < 16; j += 4) {
        uint4 v = *(const uint4*)(gV + j);
        Vs[(c0 + j + 0) * LDK + trow] = v.x;
        Vs[(c0 + j + 1) * LDK + trow] = v.y;
        Vs[(c0 + j + 2) * LDK + trow] = v.z;
        Vs[(c0 + j + 3) * LDK + trow] = v.w;
      }
    }
    __syncthreads();

    f32x4 sfr[4];
#pragma unroll
    for (int kb = 0; kb < 4; kb++) {
      f32x4 sa = zero;
#pragma unroll
      for (int kk = 0; kk < 2; kk++) {
        u32 t[8];
        bf16x8 kh, kl;
        const u32* p = Ks + (kb * 16 + (l & 15)) * LDK + kk * 32 + ((l >> 4) << 3);
        *(uint4*)t = *(const uint4*)p;
        *(uint4*)(t + 4) = *(const uint4*)(p + 4);
        unpack8(t, kh, kl);
        sa = MFMA_BF16(ql[kk], kl, sa);
        sa = MFMA_BF16(ql[kk], kh, sa);
        sa = MFMA_BF16(qh[kk], kl, sa);
        sa = MFMA_BF16(qh[kk], kh, sa);
      }
      sfr[kb] = sa * 0.125f;
    }
    if (kt == qt) {
#pragma unroll
      for (int kb = 0; kb < 4; kb++) {
        int t = kt * 64 + kb * 16 + (l & 15);
#pragma unroll
        for (int r = 0; r < 4; r++) {
          int qq = q0 + w * 16 + ((l >> 4) << 2) + r;
          if (t > qq) sfr[kb][r] = -3.0e38f;
        }
      }
    }
#pragma unroll
    for (int r = 0; r < 4; r++) {
      float mx = fmaxf(fmaxf(sfr[0][r], sfr[1][r]), fmaxf(sfr[2][r], sfr[3][r]));
#pragma unroll
      for (int mm = 1; mm < 16; mm <<= 1) mx = fmaxf(mx, __shfl_xor(mx, mm));
      float mnew = fmaxf(mrun[r], mx);
      float sf = __expf(mrun[r] - mnew);
      mrun[r] = mnew;
      float rs = 0.f;
#pragma unroll
      for (int kb = 0; kb < 4; kb++) {
        float p = __expf(sfr[kb][r] - mnew);
        sfr[kb][r] = p;
        rs += p;
      }
#pragma unroll
      for (int mm = 1; mm < 16; mm <<= 1) rs += __shfl_xor(rs, mm);
      lrun[r] = lrun[r] * sf + rs;
#pragma unroll
      for (int vb = 0; vb < 4; vb++) oacc[vb][r] *= sf;
    }
#pragma unroll
    for (int kb = 0; kb < 4; kb++)
#pragma unroll
      for (int r = 0; r < 4; r++)
        Ps[(w * 16 + ((l >> 4) << 2) + r) * LDK + kb * 16 + (l & 15)] = pack_hl(sfr[kb][r]);
#pragma unroll
    for (int ks = 0; ks < 2; ks++) {
      bf16x8 ph, pl;
      {
        u32 t[8];
        const u32* pp = Ps + (w * 16 + (l & 15)) * LDK + ks * 32 + ((l >> 4) << 3);
        *(uint4*)t = *(const uint4*)pp;
        *(uint4*)(t + 4) = *(const uint4*)(pp + 4);
        unpack8(t, ph, pl);
      }
#pragma unroll
      for (int vb = 0; vb < 4; vb++) {
        u32 t2[8];
        bf16x8 vh, vl;
        const u32* pv = Vs + (vb * 16 + (l & 15)) * LDK + ks * 32 + ((l >> 4) << 3);
        *(uint4*)t2 = *(const uint4*)pv;
        *(uint4*)(t2 + 4) = *(const uint4*)(pv + 4);
        unpack8(t2, vh, vl);
        f32x4 c = oacc[vb];
        c = MFMA_BF16(pl, vl, c);
        c = MFMA_BF16(pl, vh, c);
        c = MFMA_BF16(ph, vl, c);
        c = MFMA_BF16(ph, vh, c);
        oacc[vb] = c;
      }
    }
  }
#pragma unroll
  for (int vb = 0; vb < 4; vb++)
#pragma unroll
    for (int r = 0; r < 4; r++) {
      float o = oacc[vb][r] / lrun[r];
      int row = q0 + w * 16 + ((l >> 4) << 2) + r;
      int col = hc + vb * 16 + (l & 15);
      Op[(size_t)row * kD + col] = pack_hl(o);
    }
}

// ---------- router ----------
__global__ __launch_bounds__(256) void router_kernel(
    const float* __restrict__ normed, const float* __restrict__ Wg,
    float* __restrict__ probs, float* __restrict__ gates,
    int* __restrict__ experts, int* __restrict__ counts) {
  const int w = threadIdx.x >> 6, l = threadIdx.x & 63;
  const int s = blockIdx.x * 4 + w;
  float lg[kE];
  const float* row = normed + (size_t)s * kD;
#pragma unroll
  for (int e = 0; e < kE; e++) {
    const float* wg = Wg + (size_t)e * kD;
    float a = 0.f;
    for (int d = l; d < kD; d += 64) a += row[d] * wg[d];
#pragma unroll
    for (int m = 32; m; m >>= 1) a += __shfl_xor(a, m);
    lg[e] = a;
  }
  if (l == 0) {
    float mx = lg[0];
#pragma unroll
    for (int e = 1; e < kE; e++) mx = fmaxf(mx, lg[e]);
    float p[kE], sum = 0.f;
#pragma unroll
    for (int e = 0; e < kE; e++) { p[e] = __expf(lg[e] - mx); sum += p[e]; }
    float inv = 1.f / sum;
#pragma unroll
    for (int e = 0; e < kE; e++) { p[e] *= inv; probs[(size_t)s * kE + e] = p[e]; }
    int i1 = 0;
#pragma unroll
    for (int e = 1; e < kE; e++) if (lg[e] > lg[i1]) i1 = e;
    int i2 = (i1 == 0) ? 1 : 0;
#pragma unroll
    for (int e = 0; e < kE; e++) if (e != i1 && lg[e] > lg[i2]) i2 = e;
    float den = 1.f / (p[i1] + p[i2]);
    gates[s * 2] = p[i1] * den;
    gates[s * 2 + 1] = p[i2] * den;
    experts[s * 2] = i1;
    experts[s * 2 + 1] = i2;
    atomicAdd(&counts[i1], 1);
    atomicAdd(&counts[i2], 1);
  }
}

__global__ void moe_init(int* counts) {
  if (threadIdx.x < kE) counts[threadIdx.x] = 0;
}
__global__ void moe_scan(const int* __restrict__ counts, int* __restrict__ ebase,
                         int* __restrict__ cursor) {
  if (threadIdx.x == 0) {
    int acc = 0;
    for (int e = 0; e < kE; e++) { ebase[e] = acc; cursor[e] = acc; acc += counts[e]; }
    ebase[kE] = acc;
  }
}
__global__ void moe_fill(const int* __restrict__ experts, int* __restrict__ cursor,
                         int* __restrict__ slot_list, int* __restrict__ slot_of) {
  int s = blockIdx.x * 256 + threadIdx.x;
  if (s >= kS) return;
  for (int k = 0; k < 2; k++) {
    int e = experts[s * 2 + k];
    int pos = atomicAdd(&cursor[e], 1);
    slot_list[pos] = s;
    slot_of[s * 2 + k] = pos;
  }
}

// ---------- MoE fused GEMM: counted-vmcnt 2-phase ----------
__global__ __launch_bounds__(512) void moe_mm1(
    const u16* __restrict__ A, const u16* __restrict__ B1g, const u16* __restrict__ B2g,
    const int* __restrict__ slot_list, const int* __restrict__ ebase,
    u16* __restrict__ Uo) {
  const int e = blockIdx.z;
  const int base = ebase[e];
  const int Me = ebase[e + 1] - base;
  const int m0 = blockIdx.y * 256;
  if (m0 >= Me) return;
  const int n0 = blockIdx.x * 128;
  __shared__ u16 As[2][256 * 64];
  __shared__ u16 B1s[2][128 * 64];
  __shared__ u16 B2s[2][128 * 64];
  const int tid = threadIdx.x, w = tid >> 6, l = tid & 63;
  const int wr = (w >> 2) * 128, wc = (w & 3) * 32;
  const char* B1 = (const char*)(B1g + (size_t)e * kFF * kD);
  const char* B2 = (const char*)(B2g + (size_t)e * kFF * kD);

  size_t asrc[4], bsrc[2];
  int adst[4], bdst[2];
#pragma unroll
  for (int i = 0; i < 4; i++) {
    int fl = i * 512 + tid;
    int row = fl >> 3, cb = fl & 7;
    int mr = m0 + row;
    if (mr > Me - 1) mr = Me - 1;
    int ar = slot_list[base + mr];
    asrc[i] = (size_t)ar * 2048 + (size_t)((cb ^ (row & 7)) * 16);
    adst[i] = fl * 16;
  }
#pragma unroll
  for (int i = 0; i < 2; i++) {
    int fl = i * 512 + tid;
    int row = fl >> 3, cb = fl & 7;
    bsrc[i] = (size_t)(n0 + row) * 2048 + (size_t)((cb ^ (row & 7)) * 16);
    bdst[i] = fl * 16;
  }

  f32x4 zero = {0.f, 0.f, 0.f, 0.f};
  f32x4 acc1[8][2], acc2[8][2];
#pragma unroll
  for (int i = 0; i < 8; i++)
#pragma unroll
    for (int j = 0; j < 2; j++) { acc1[i][j] = zero; acc2[i][j] = zero; }

  auto stage = [&](int buf, int s) {
    const size_t so = (size_t)s * 128;
    const char* ab = (const char*)A + so;
#pragma unroll
    for (int i = 0; i < 4; i++) gload_lds16(ab + asrc[i], (char*)&As[buf][0] + adst[i]);
#pragma unroll
    for (int i = 0; i < 2; i++) {
      gload_lds16(B1 + so + bsrc[i], (char*)&B1s[buf][0] + bdst[i]);
      gload_lds16(B2 + so + bsrc[i], (char*)&B2s[buf][0] + bdst[i]);
    }
  };

  const int NS = kD / 64;  // 16
  stage(0, 0);
  for (int s = 0; s < NS; s++) {
    const int cur = s & 1;
    const bool lastit = (s == NS - 1);
    if (!lastit) stage(cur ^ 1, s + 1);
    if (!lastit) VMCNT8(); else VMCNT0();
    SBAR();
    SCHED0();
#pragma unroll
    for (int kk = 0; kk < 2; kk++) {
      const int g = kk * 4 + (l >> 4);
      bf16x8 af[8], b1f[2], b2f[2];
#pragma unroll
      for (int mi = 0; mi < 8; mi++) {
        int row = wr + mi * 16 + (l & 15);
        af[mi] = *(const bf16x8*)&As[cur][row * 64 + ((g ^ (row & 7)) * 8)];
      }
#pragma unroll
      for (int ni = 0; ni < 2; ni++) {
        int row = wc + ni * 16 + (l & 15);
        int bo = row * 64 + ((g ^ (row & 7)) * 8);
        b1f[ni] = *(const bf16x8*)&B1s[cur][bo];
        b2f[ni] = *(const bf16x8*)&B2s[cur][bo];
      }
#pragma unroll
      for (int mi = 0; mi < 8; mi++)
#pragma unroll
        for (int ni = 0; ni < 2; ni++) {
          acc1[mi][ni] = MFMA_BF16(af[mi], b1f[ni], acc1[mi][ni]);
          acc2[mi][ni] = MFMA_BF16(af[mi], b2f[ni], acc2[mi][ni]);
        }
    }
    SCHED0();
    if (!lastit) SBAR();
  }

#pragma unroll
  for (int mi = 0; mi < 8; mi++)
#pragma unroll
    for (int r = 0; r < 4; r++) {
      int ml = m0 + wr + mi * 16 + ((l >> 4) << 2) + r;
      if (ml >= Me) continue;
      size_t rb = (size_t)(base + ml) * kFF;
#pragma unroll
      for (int ni = 0; ni < 2; ni++) {
        int col = n0 + wc + ni * 16 + (l & 15);
        float u = acc1[mi][ni][r], v2 = acc2[mi][ni][r];
        float ge = 0.5f * u * (1.0f + erff(u * 0.70710678118654752f));
        Uo[rb + col] = bf16_rne(ge * v2);
      }
    }
}

// ---------- MoE out GEMM: counted-vmcnt 2-phase ----------
__global__ __launch_bounds__(256) void moe_mm2(
    const u16* __restrict__ U, const u16* __restrict__ Bg,
    const int* __restrict__ ebase, float* __restrict__ eo) {
  const int e = blockIdx.z;
  const int base = ebase[e];
  const int Me = ebase[e + 1] - base;
  const int m0 = blockIdx.y * 128;
  if (m0 >= Me) return;
  const int n0 = blockIdx.x * 128;
  __shared__ u16 As[2][128 * 64];
  __shared__ u16 Bs[2][128 * 64];
  const int tid = threadIdx.x, w = tid >> 6, l = tid & 63;
  const int wr = (w >> 1) * 64, wc = (w & 1) * 64;
  const char* B = (const char*)(Bg + (size_t)e * kD * kFF);

  size_t asrc[4], bsrc[4];
  int dst[4];
#pragma unroll
  for (int i = 0; i < 4; i++) {
    int fl = i * 256 + tid;
    int row = fl >> 3, cb = fl & 7;
    size_t coff = (size_t)((cb ^ (row & 7)) * 16);
    int mr = m0 + row;
    if (mr > Me - 1) mr = Me - 1;
    asrc[i] = (size_t)(base + mr) * 8192 + coff;
    bsrc[i] = (size_t)(n0 + row) * 8192 + coff;
    dst[i] = fl * 16;
  }

  f32x4 zero = {0.f, 0.f, 0.f, 0.f};
  f32x4 acc[4][4];
#pragma unroll
  for (int i = 0; i < 4; i++)
#pragma unroll
    for (int j = 0; j < 4; j++) acc[i][j] = zero;

  auto stage = [&](int buf, int s) {
    const size_t so = (size_t)s * 128;
#pragma unroll
    for (int i = 0; i < 4; i++) {
      gload_lds16((const char*)U + so + asrc[i], (char*)&As[buf][0] + dst[i]);
      gload_lds16(B + so + bsrc[i], (char*)&Bs[buf][0] + dst[i]);
    }
  };

  const int NS = kFF / 64;  // 64
  stage(0, 0);
  for (int s = 0; s < NS; s++) {
    const int cur = s & 1;
    const bool lastit = (s == NS - 1);
    if (!lastit) stage(cur ^ 1, s + 1);
    if (!lastit) VMCNT8(); else VMCNT0();
    SBAR();
    SCHED0();
#pragma unroll
    for (int kk = 0; kk < 2; kk++) {
      const int g = kk * 4 + (l >> 4);
      bf16x8 af[4], bf[4];
#pragma unroll
      for (int mi = 0; mi < 4; mi++) {
        int row = wr + mi * 16 + (l & 15);
        af[mi] = *(const bf16x8*)&As[cur][row * 64 + ((g ^ (row & 7)) * 8)];
      }
#pragma unroll
      for (int ni = 0; ni < 4; ni++) {
        int row = wc + ni * 16 + (l & 15);
        bf[ni] = *(const bf16x8*)&Bs[cur][row * 64 + ((g ^ (row & 7)) * 8)];
      }
#pragma unroll
      for (int mi = 0; mi < 4; mi++)
#pragma unroll
        for (int ni = 0; ni < 4; ni++) acc[mi][ni] = MFMA_BF16(af[mi], bf[ni], acc[mi][ni]);
    }
    SCHED0();
    if (!lastit) SBAR();
  }

#pragma unroll
  for (int mi = 0; mi < 4; mi++)
#pragma unroll
    for (int r = 0; r < 4; r++) {
      int ml = m0 + wr + mi * 16 + ((l >> 4) << 2) + r;
      if (ml >= Me) continue;
      size_t rb = (size_t)(base + ml) * kD;
#pragma unroll
      for (int ni = 0; ni < 4; ni++) {
        int col = n0 + wc + ni * 16 + (l & 15);
        eo[rb + col] = acc[mi][ni][r];
      }
    }
}

// ---------- final combine ----------
__global__ __launch_bounds__(256) void combine_kernel(
    const float* __restrict__ h, const float* __restrict__ eo,
    const float* __restrict__ gates, const int* __restrict__ slot_of,
    float* __restrict__ out) {
  const int s = blockIdx.x;
  const float g0 = gates[s * 2], g1 = gates[s * 2 + 1];
  const int p0 = slot_of[s * 2], p1 = slot_of[s * 2 + 1];
  const int c = threadIdx.x * 4;
  float4 hv = *(const float4*)(h + (size_t)s * kD + c);
  float4 e0 = *(const float4*)(eo + (size_t)p0 * kD + c);
  float4 e1 = *(const float4*)(eo + (size_t)p1 * kD + c);
  float4 o;
  o.x = hv.x + g0 * e0.x + g1 * e1.x;
  o.y = hv.y + g0 * e0.y + g1 * e1.y;
  o.z = hv.z + g0 * e0.z + g1 * e1.z;
  o.w = hv.w + g0 * e0.w + g1 * e1.w;
  *(float4*)(out + (size_t)s * kD + c) = o;
}

extern "C" void kernel_launch(void* const* d_in, const int* in_sizes, int n_in,
                              void* d_out, int out_size, void* d_ws, size_t ws_size,
                              hipStream_t stream) {
  (void)in_sizes; (void)n_in; (void)out_size; (void)ws_size;
  const float* x = (const float*)d_in[0];
  const float* scale_attn = (const float*)d_in[2];
  const float* Wq = (const float*)d_in[3];
  const float* Wk = (const float*)d_in[4];
  const float* Wv = (const float*)d_in[5];
  const float* Wo = (const float*)d_in[6];
  const float* scale_ffn = (const float*)d_in[7];
  const float* Wg = (const float*)d_in[8];
  const float* W_in = (const float*)d_in[9];
  const float* W_vv = (const float*)d_in[10];
  const float* W_out = (const float*)d_in[11];
  float* out = (float*)d_out;
  float* probs = out + (size_t)kS * kD;

  char* wsb = (char*)d_ws;
  size_t off = 0;
  auto alloc = [&](size_t bytes) -> void* {
    void* p = wsb + off;
    off += (bytes + 255) & ~(size_t)255;
    return p;
  };
  const size_t SDu = (size_t)kS * kD;
  const size_t EW = (size_t)kE * kFF * kD;
  u16* normA_dp = (u16*)alloc(SDu * 2 * 2);
  u32* qpk = (u32*)alloc(SDu * 4);
  u32* kpk = (u32*)alloc(SDu * 4);
  u32* vpk = (u32*)alloc(SDu * 4);
  u32* ctxpk = (u32*)alloc(SDu * 4);
  float* h = (float*)alloc(SDu * 4);
  float* normFf = (float*)alloc(SDu * 4);
  u16* normFb = (u16*)alloc(SDu * 2);
  u16* Wqkv_dp = (u16*)alloc((size_t)3072 * 2048 * 2);
  u16* Wo_dp = (u16*)alloc((size_t)1024 * 2048 * 2);
  u16* Win_bf = (u16*)alloc(EW * 2);
  u16* Wv_bf = (u16*)alloc(EW * 2);
  u16* Wout_bf = (u16*)alloc(EW * 2);
  u16* U = (u16*)alloc((size_t)kSlots * kFF * 2);
  float* eo = (float*)alloc((size_t)kSlots * kD * 4);
  float* gates = (float*)alloc(kS * 2 * 4);
  int* experts = (int*)alloc(kS * 2 * 4);
  int* slot_of = (int*)alloc(kS * 2 * 4);
  int* slot_list = (int*)alloc(kSlots * 4);
  int* counts = (int*)alloc(64);
  int* ebase = (int*)alloc(64);
  int* cursor = (int*)alloc(64);

  pack_dp3<<<(3072 * 1024) / 256, 256, 0, stream>>>(Wq, Wk, Wv, Wqkv_dp);
  pack_dp1<<<(1024 * 1024) / 256, 256, 0, stream>>>(Wo, Wo_dp, 1024 * 1024);
  const int n8 = (int)(EW / 8);
  pack_bf16_kernel<<<(n8 + 255) / 256, 256, 0, stream>>>(W_in, Win_bf, n8);
  pack_bf16_kernel<<<(n8 + 255) / 256, 256, 0, stream>>>(W_vv, Wv_bf, n8);
  pack_bf16_kernel<<<(n8 + 255) / 256, 256, 0, stream>>>(W_out, Wout_bf, n8);

  rmsnorm_kernel<0><<<kS, 256, 0, stream>>>(x, scale_attn, normA_dp, nullptr, nullptr);
  gemm_dp<0, 0><<<dim3(3072 / 128, kS / 128), 256, 0, stream>>>(
      normA_dp, Wqkv_dp, nullptr, kD, qpk, kpk, vpk, nullptr);
  attn_kernel<<<dim3(kS / 64, kH), 256, 0, stream>>>(qpk, kpk, vpk, ctxpk);
  gemm_dp<1, 1><<<dim3(1024 / 128, kS / 128), 256, 0, stream>>>(
      ctxpk, Wo_dp, x, kD, nullptr, nullptr, nullptr, h);

  rmsnorm_kernel<1><<<kS, 256, 0, stream>>>(h, scale_ffn, nullptr, normFf, normFb);
  moe_init<<<1, 64, 0, stream>>>(counts);
  router_kernel<<<kS / 4, 256, 0, stream>>>(normFf, Wg, probs, gates, experts, counts);
  moe_scan<<<1, 64, 0, stream>>>(counts, ebase, cursor);
  moe_fill<<<kS / 256, 256, 0, stream>>>(experts, cursor, slot_list, slot_of);

  moe_mm1<<<dim3(kFF / 128, kSlots / 256, kE), 512, 0, stream>>>(
      normFb, Win_bf, Wv_bf, slot_list, ebase, U);
  moe_mm2<<<dim3(kD / 128, kSlots / 128, kE), 256, 0, stream>>>(
      U, Wout_bf, ebase, eo);

  combine_kernel<<<kS, 256, 0, stream>>>(h, eo, gates, slot_of, out);
}